// Round 3
// baseline (3430.626 us; speedup 1.0000x reference)
//
#include <hip/hip_runtime.h>
#include <stdint.h>

// ---------------------------------------------------------------------------
// UserSpotConv: bipartite GCN aggregation.
//   user_out[u] = isd_u[u] * sum_{e: u_e=u} spot_x[s_e] * isd_s[s_e]
//   spot_out[s] = isd_s[s] * sum_{e: s_e=s} user_x[u_e] * isd_u[u_e]
// Round 3: the CSR gather was fetch-bound (420 MB FETCH/dir, 2 TB/s).
//  - convert features to bf16 PRE-SCALED by isd_src (halves bytes, kills the
//    random isd load)
//  - bsort2: order each bucket's edges by coarse src bin -> all blocks sweep
//    the feature table together -> per-XCD L2 holds a moving window
//  - accum: block per 64-node bucket, f32 accumulator in LDS (ds_add_f32,
//    stride-1 via permuted row layout), 2-deep pipelined row loads
// ---------------------------------------------------------------------------

#define NPB_LOG2 6
#define NPB 64             // destination nodes per bucket
#define MAXB 768           // max buckets supported by part_kernel LDS
#define PART_CHUNK 12288   // edges per block in part_kernel
#define SORT_CAP 12288     // max edges per bucket for bsort2 staging

__device__ __forceinline__ ushort f2bf(float f) {
    uint32_t u = __float_as_uint(f);
    return (ushort)((u + 0x7fffu + ((u >> 16) & 1u)) >> 16);  // RNE
}

__global__ void deg_kernel(const int* __restrict__ u, const int* __restrict__ s,
                           int E, int* __restrict__ udeg, int* __restrict__ sdeg) {
    int i = blockIdx.x * blockDim.x + threadIdx.x;
    int i4 = i * 4;
    if (i4 + 3 < E) {
        int4 a = *reinterpret_cast<const int4*>(u + i4);
        int4 b = *reinterpret_cast<const int4*>(s + i4);
        atomicAdd(&udeg[a.x], 1); atomicAdd(&udeg[a.y], 1);
        atomicAdd(&udeg[a.z], 1); atomicAdd(&udeg[a.w], 1);
        atomicAdd(&sdeg[b.x], 1); atomicAdd(&sdeg[b.y], 1);
        atomicAdd(&sdeg[b.z], 1); atomicAdd(&sdeg[b.w], 1);
    } else {
        for (int k = i4; k < E; ++k) {
            atomicAdd(&udeg[u[k]], 1);
            atomicAdd(&sdeg[s[k]], 1);
        }
    }
}

// Exclusive scan, single block of 1024 threads, 4 elems/thread per chunk.
__global__ __launch_bounds__(1024) void scan_kernel(const int* __restrict__ in,
                                                    int* __restrict__ out, int n) {
    __shared__ int ws[17];
    const int tid  = threadIdx.x;
    const int lane = tid & 63;
    const int wid  = tid >> 6;
    int carry = 0;  // meaningful on tid 0 only
    for (int base = 0; base < n; base += 4096) {
        int idx = base + tid * 4;
        int v0 = (idx + 0 < n) ? in[idx + 0] : 0;
        int v1 = (idx + 1 < n) ? in[idx + 1] : 0;
        int v2 = (idx + 2 < n) ? in[idx + 2] : 0;
        int v3 = (idx + 3 < n) ? in[idx + 3] : 0;
        int tsum = v0 + v1 + v2 + v3;
        int x = tsum;
#pragma unroll
        for (int d = 1; d < 64; d <<= 1) {
            int t = __shfl_up(x, d);
            if (lane >= d) x += t;
        }
        if (lane == 63) ws[wid] = x;
        __syncthreads();
        if (tid == 0) {
            int run = carry;
#pragma unroll
            for (int w = 0; w < 16; ++w) { int t = ws[w]; ws[w] = run; run += t; }
            carry = run;
        }
        __syncthreads();
        int excl = ws[wid] + (x - tsum);
        if (idx + 0 < n) out[idx + 0] = excl; excl += v0;
        if (idx + 1 < n) out[idx + 1] = excl; excl += v1;
        if (idx + 2 < n) out[idx + 2] = excl; excl += v2;
        if (idx + 3 < n) out[idx + 3] = excl;
        __syncthreads();
    }
    if (tid == 0) out[n] = carry;
}

__global__ void init_isd_kernel(const int* __restrict__ udeg, const int* __restrict__ sdeg,
                                float* __restrict__ isd_u, float* __restrict__ isd_s,
                                int n_user, int m_spot) {
    int i = blockIdx.x * blockDim.x + threadIdx.x;
    if (i < n_user) { int d = udeg[i]; isd_u[i] = d > 0 ? rsqrtf((float)d) : 0.f; }
    if (i < m_spot) { int d = sdeg[i]; isd_s[i] = d > 0 ? rsqrtf((float)d) : 0.f; }
}

// xb row layout is PERMUTED: slot 2c   holds col c      (c in [0,64))
//                            slot 2c+1 holds col c+64
// so accum lane l's uint32 load at +4*l yields cols (l, l+64) -> ds_add_f32
// addresses are stride-1 per instruction (free 2-way banking).
__global__ void convert_kernel(const float* __restrict__ x, const float* __restrict__ isd,
                               ushort* __restrict__ xb, int n_rows) {
    int idx = blockIdx.x * blockDim.x + threadIdx.x;
    if (idx >= (n_rows << 6)) return;
    int row = idx >> 6, c = idx & 63;
    float w = isd[row];
    const float* xr = x + ((size_t)row << 7);
    ushort2 o;
    o.x = f2bf(xr[c] * w);
    o.y = f2bf(xr[c + 64] * w);
    *reinterpret_cast<ushort2*>(xb + ((size_t)row << 7) + 2 * c) = o;
}

__global__ void gcur_init_kernel(const int* __restrict__ uoff, const int* __restrict__ soff,
                                 int* __restrict__ gcur_u, int* __restrict__ gcur_s,
                                 int nbu, int nbs) {
    int i = blockIdx.x * blockDim.x + threadIdx.x;
    if (i < nbu) gcur_u[i] = uoff[i << NPB_LOG2];
    if (i < nbs) gcur_s[i] = soff[i << NPB_LOG2];
}

// Partition edges into NPB-node buckets of the primary (destination) index.
__global__ __launch_bounds__(256) void part_kernel(
        const int* __restrict__ prim, const int* __restrict__ sec, int E,
        int nb, int* __restrict__ gcur, uint32_t* __restrict__ out) {
    __shared__ int hist[MAXB];
    __shared__ int loff[MAXB + 1];
    __shared__ int gbase[MAXB];
    __shared__ int cur[MAXB];
    __shared__ uint32_t sbuf[PART_CHUNK];
    const int tid = threadIdx.x;
    const int beg = blockIdx.x * PART_CHUNK;
    const int end = min(beg + PART_CHUNK, E);
    for (int b = tid; b < nb; b += 256) hist[b] = 0;
    __syncthreads();
    for (int i = beg + tid; i < end; i += 256)
        atomicAdd(&hist[prim[i] >> NPB_LOG2], 1);
    __syncthreads();
    if (tid == 0) {
        int run = 0;
        for (int b = 0; b < nb; ++b) { loff[b] = run; run += hist[b]; }
        loff[nb] = run;
    }
    __syncthreads();
    for (int b = tid; b < nb; b += 256) {
        cur[b] = loff[b];
        int c = loff[b + 1] - loff[b];
        gbase[b] = c > 0 ? atomicAdd(&gcur[b], c) : 0;
    }
    __syncthreads();
    for (int i = beg + tid; i < end; i += 256) {
        int p = prim[i], s = sec[i];
        int b = p >> NPB_LOG2;
        int l = atomicAdd(&cur[b], 1);
        sbuf[l] = ((uint32_t)p << 16) | (uint32_t)s;
    }
    __syncthreads();
    const int wid = tid >> 6, lane = tid & 63;
    for (int b = wid; b < nb; b += 4) {
        int lo = loff[b], cnt = loff[b + 1] - lo, gb = gbase[b];
        for (int k = lane; k < cnt; k += 64)
            out[gb + k] = sbuf[lo + k];
    }
}

// Reorder one bucket's edge segment by coarse source bin (src>>8), in place.
// Perf-only (any order is correct); gives all accum blocks a synchronized
// sweep of the source feature table -> L2-resident moving window.
__global__ __launch_bounds__(256) void bsort2_kernel(
        uint32_t* __restrict__ buf, const int* __restrict__ off, int n_rows) {
    __shared__ uint32_t stage[SORT_CAP];
    __shared__ int hist[256];
    __shared__ int cur[256];
    const int tid = threadIdx.x;
    const int ubase = blockIdx.x << NPB_LOG2;
    const int nin = min(NPB, n_rows - ubase);
    const int jbeg = off[ubase];
    const int cnt = off[ubase + nin] - jbeg;
    if (cnt > SORT_CAP) return;     // statistically impossible here; order is perf-only
    hist[tid] = 0;
    __syncthreads();
    for (int k = tid; k < cnt; k += 256) {
        uint32_t p = buf[jbeg + k];
        stage[k] = p;
        atomicAdd(&hist[(p & 0xffffu) >> 8], 1);
    }
    __syncthreads();   // also drains global reads (vmcnt) before we overwrite
    if (tid == 0) {
        int run = 0;
        for (int b = 0; b < 256; ++b) { int t = hist[b]; cur[b] = run; run += t; }
    }
    __syncthreads();
    for (int k = tid; k < cnt; k += 256) {
        uint32_t p = stage[k];
        int pos = atomicAdd(&cur[(p & 0xffffu) >> 8], 1);
        buf[jbeg + pos] = p;
    }
}

// One block per 64-node bucket: accumulate pre-scaled bf16 rows into a 32 KB
// f32 LDS accumulator, then post-scale by isd_dst and write out.
__global__ __launch_bounds__(512) void accum_kernel(
        const ushort* __restrict__ xb, const uint32_t* __restrict__ packed,
        const int* __restrict__ off, const float* __restrict__ isd_dst,
        float* __restrict__ out, int n_rows) {
    __shared__ float acc[NPB * 128];
    const int tid = threadIdx.x;
    const int ubase = blockIdx.x << NPB_LOG2;
    const int nin = min(NPB, n_rows - ubase);
    for (int k = tid; k < NPB * 128; k += 512) acc[k] = 0.f;
    __syncthreads();
    const int jbeg = off[ubase];
    const int jend = off[ubase + nin];
    const int wid = tid >> 6, lane = tid & 63;
    int j = jbeg + wid;
    for (; j + 8 < jend; j += 16) {       // 2-deep pipelined row loads
        uint32_t p0 = packed[j];
        uint32_t p1 = packed[j + 8];
        uint32_t v0 = *reinterpret_cast<const uint32_t*>(
            xb + ((size_t)(p0 & 0xffffu) << 7) + lane * 2);
        uint32_t v1 = *reinterpret_cast<const uint32_t*>(
            xb + ((size_t)(p1 & 0xffffu) << 7) + lane * 2);
        int l0 = ((int)(p0 >> 16) - ubase) << 7;
        int l1 = ((int)(p1 >> 16) - ubase) << 7;
        atomicAdd(&acc[l0 + lane],      __uint_as_float(v0 << 16));
        atomicAdd(&acc[l0 + 64 + lane], __uint_as_float(v0 & 0xffff0000u));
        atomicAdd(&acc[l1 + lane],      __uint_as_float(v1 << 16));
        atomicAdd(&acc[l1 + 64 + lane], __uint_as_float(v1 & 0xffff0000u));
    }
    for (; j < jend; j += 8) {
        uint32_t p0 = packed[j];
        uint32_t v0 = *reinterpret_cast<const uint32_t*>(
            xb + ((size_t)(p0 & 0xffffu) << 7) + lane * 2);
        int l0 = ((int)(p0 >> 16) - ubase) << 7;
        atomicAdd(&acc[l0 + lane],      __uint_as_float(v0 << 16));
        atomicAdd(&acc[l0 + 64 + lane], __uint_as_float(v0 & 0xffff0000u));
    }
    __syncthreads();
    for (int r = wid; r < nin; r += 8) {
        float w = isd_dst[ubase + r];
        float2 v = *reinterpret_cast<const float2*>(&acc[(r << 7) + lane * 2]);
        float2 o; o.x = v.x * w; o.y = v.y * w;
        *reinterpret_cast<float2*>(out + (((size_t)(ubase + r)) << 7) + lane * 2) = o;
    }
}

// ---- fallback path kernels (round-2 proven CSR gather, f32 features) ------

__global__ __launch_bounds__(256) void bsort_kernel(
        const uint32_t* __restrict__ packed, const int* __restrict__ noff,
        int nodes, int* __restrict__ csr) {
    __shared__ int cur[NPB];
    const int tid = threadIdx.x;
    const int ubase = blockIdx.x << NPB_LOG2;
    const int nin = min(NPB, nodes - ubase);
    if (tid < nin) cur[tid] = noff[ubase + tid];
    __syncthreads();
    const int jbeg = noff[ubase];
    const int jend = noff[ubase + nin];
    for (int j = jbeg + tid; j < jend; j += 256) {
        uint32_t p = packed[j];
        int local = (int)(p >> 16) - ubase;
        int slot = atomicAdd(&cur[local], 1);
        csr[slot] = (int)(p & 0xffffu);
    }
}

__global__ __launch_bounds__(256) void gather_kernel(const float* __restrict__ x_src,
                                                     const int* __restrict__ nbr,
                                                     const int* __restrict__ off,
                                                     const float* __restrict__ isd_dst,
                                                     const float* __restrict__ isd_src,
                                                     float* __restrict__ out, int n_rows) {
    const int lane = threadIdx.x & 63;
    const int row  = blockIdx.x * 4 + (threadIdx.x >> 6);
    if (row >= n_rows) return;
    const int jbeg = off[row];
    const int jend = off[row + 1];
    const float wd = isd_dst[row];
    float ax = 0.f, ay = 0.f;
    if (jbeg < jend) {
        int sidx = nbr[jbeg];
        for (int j = jbeg; j < jend; ++j) {
            int snext = (j + 1 < jend) ? nbr[j + 1] : 0;
            float w = wd * isd_src[sidx];
            const float2 v = *reinterpret_cast<const float2*>(x_src + (size_t)sidx * 128 + lane * 2);
            ax = fmaf(v.x, w, ax);
            ay = fmaf(v.y, w, ay);
            sidx = snext;
        }
    }
    float2 r; r.x = ax; r.y = ay;
    *reinterpret_cast<float2*>(out + (size_t)row * 128 + lane * 2) = r;
}

__global__ __launch_bounds__(256) void scatter_kernel(const float* __restrict__ spot_x,
                                                      const float* __restrict__ user_x,
                                                      const int* __restrict__ u,
                                                      const int* __restrict__ s, int E,
                                                      const float* __restrict__ isd_u,
                                                      const float* __restrict__ isd_s,
                                                      float* __restrict__ spot_out,
                                                      float* __restrict__ user_out) {
    const int lane = threadIdx.x & 63;
    const int e = blockIdx.x * 4 + (threadIdx.x >> 6);
    if (e >= E) return;
    const int uu = u[e], ss = s[e];
    const float w = isd_u[uu] * isd_s[ss];
    const float2 sv = *reinterpret_cast<const float2*>(spot_x + (size_t)ss * 128 + lane * 2);
    const float2 uv = *reinterpret_cast<const float2*>(user_x + (size_t)uu * 128 + lane * 2);
    atomicAdd(&user_out[(size_t)uu * 128 + lane * 2 + 0], sv.x * w);
    atomicAdd(&user_out[(size_t)uu * 128 + lane * 2 + 1], sv.y * w);
    atomicAdd(&spot_out[(size_t)ss * 128 + lane * 2 + 0], uv.x * w);
    atomicAdd(&spot_out[(size_t)ss * 128 + lane * 2 + 1], uv.y * w);
}

extern "C" void kernel_launch(void* const* d_in, const int* in_sizes, int n_in,
                              void* d_out, int out_size, void* d_ws, size_t ws_size,
                              hipStream_t stream) {
    const float* spot_x = (const float*)d_in[0];
    const float* user_x = (const float*)d_in[1];
    const int*   edges  = (const int*)d_in[2];
    const int M = in_sizes[0] / 128;   // spots
    const int N = in_sizes[1] / 128;   // users
    const int E = in_sizes[2] / 2;
    const int* u = edges;        // user_spot[0]
    const int* s = edges + E;    // user_spot[1]
    float* spot_out = (float*)d_out;
    float* user_out = (float*)d_out + (size_t)M * 128;

    const int nbu = (N + NPB - 1) / NPB;
    const int nbs = (M + NPB - 1) / NPB;

    // Workspace layout (fallback-critical arrays first).
    char* ws = (char*)d_ws;
    int*      udeg  = (int*)ws;      ws += sizeof(int) * N;     // udeg+sdeg contiguous (memset)
    int*      sdeg  = (int*)ws;      ws += sizeof(int) * M;
    float*    isd_u = (float*)ws;    ws += sizeof(float) * N;
    float*    isd_s = (float*)ws;    ws += sizeof(float) * M;
    size_t fallback_needed = (size_t)(ws - (char*)d_ws);
    int*      uoff  = (int*)ws;      ws += sizeof(int) * (N + 1);
    int*      soff  = (int*)ws;      ws += sizeof(int) * (M + 1);
    int*      gcu   = (int*)ws;      ws += sizeof(int) * nbu;
    int*      gcs   = (int*)ws;      ws += sizeof(int) * nbs;
    uint32_t* bufA  = (uint32_t*)ws; ws += sizeof(uint32_t) * (size_t)E;  // packed edges
    char* mark = ws;
    // union A (new path): bf16 pre-scaled feature tables
    ushort*   xbs   = (ushort*)mark;                      // spot features [M][128]
    ushort*   xbu   = (ushort*)(mark + sizeof(ushort) * ((size_t)M * 128));
    size_t new_needed = (size_t)(mark - (char*)d_ws) + sizeof(ushort) * 128 * ((size_t)M + N);
    // union B (old path): CSR neighbor buffer
    int*      bufB  = (int*)mark;
    size_t old_needed = (size_t)(mark - (char*)d_ws) + sizeof(int) * (size_t)E;

    hipMemsetAsync(udeg, 0, sizeof(int) * (size_t)(N + M), stream);
    deg_kernel<<<(E / 4 + 255) / 256, 256, 0, stream>>>(u, s, E, udeg, sdeg);
    scan_kernel<<<1, 1024, 0, stream>>>(udeg, uoff, N);
    scan_kernel<<<1, 1024, 0, stream>>>(sdeg, soff, M);
    const int nm = (N > M) ? N : M;
    init_isd_kernel<<<(nm + 255) / 256, 256, 0, stream>>>(udeg, sdeg, isd_u, isd_s, N, M);

    const int gpart = (E + PART_CHUNK - 1) / PART_CHUNK;
    if (new_needed <= ws_size && nbu <= MAXB && nbs <= MAXB) {
        convert_kernel<<<((M << 6) + 255) / 256, 256, 0, stream>>>(spot_x, isd_s, xbs, M);
        convert_kernel<<<((N << 6) + 255) / 256, 256, 0, stream>>>(user_x, isd_u, xbu, N);
        gcur_init_kernel<<<(nbs + 255) / 256, 256, 0, stream>>>(uoff, soff, gcu, gcs, nbu, nbs);
        // user direction: prim=u, sec=s; gather spot rows
        part_kernel<<<gpart, 256, 0, stream>>>(u, s, E, nbu, gcu, bufA);
        bsort2_kernel<<<nbu, 256, 0, stream>>>(bufA, uoff, N);
        accum_kernel<<<nbu, 512, 0, stream>>>(xbs, bufA, uoff, isd_u, user_out, N);
        // spot direction: prim=s, sec=u; gather user rows
        part_kernel<<<gpart, 256, 0, stream>>>(s, u, E, nbs, gcs, bufA);
        bsort2_kernel<<<nbs, 256, 0, stream>>>(bufA, soff, M);
        accum_kernel<<<nbs, 512, 0, stream>>>(xbu, bufA, soff, isd_s, spot_out, M);
    } else if (old_needed <= ws_size && nbu <= MAXB && nbs <= MAXB) {
        gcur_init_kernel<<<(nbs + 255) / 256, 256, 0, stream>>>(uoff, soff, gcu, gcs, nbu, nbs);
        part_kernel<<<gpart, 256, 0, stream>>>(u, s, E, nbu, gcu, bufA);
        bsort_kernel<<<nbu, 256, 0, stream>>>(bufA, uoff, N, bufB);
        gather_kernel<<<(N + 3) / 4, 256, 0, stream>>>(spot_x, bufB, uoff,
                                                       isd_u, isd_s, user_out, N);
        part_kernel<<<gpart, 256, 0, stream>>>(s, u, E, nbs, gcs, bufA);
        bsort_kernel<<<nbs, 256, 0, stream>>>(bufA, soff, M, bufB);
        gather_kernel<<<(M + 3) / 4, 256, 0, stream>>>(user_x, bufB, soff,
                                                       isd_s, isd_u, spot_out, M);
    } else if (fallback_needed <= ws_size) {
        hipMemsetAsync(d_out, 0, sizeof(float) * (size_t)out_size, stream);
        scatter_kernel<<<((size_t)E + 3) / 4, 256, 0, stream>>>(spot_x, user_x, u, s, E,
                                                                isd_u, isd_s, spot_out, user_out);
    }
}

// Round 4
// 428.311 us; speedup vs baseline: 8.0097x; 8.0097x over previous
//
#include <hip/hip_runtime.h>
#include <stdint.h>

// ---------------------------------------------------------------------------
// UserSpotConv: bipartite GCN aggregation.
//   user_out[u] = isd_u[u] * sum_{e: u_e=u} spot_x[s_e] * isd_s[s_e]
//   spot_out[s] = isd_s[s] * sum_{e: s_e=s} user_x[u_e] * isd_u[u_e]
// Round 4: round-3's LDS-atomic accumulator throttled at the LDS RMW path
// (1572 us/dir @ 2.3% VALU). Replace with dst-sorted REGISTER chunk-scan:
//   part   : bucket-group edges (proven)
//   bsort3 : per-bucket counting sort by dst (self-histogram, LDS-staged,
//            in-place; perf-only — consumer is order-agnostic)
//   cscan  : wave per 256 edges, accumulate bf16 rows in 2 VGPRs, flush on
//            dst change via native unsafeAtomicAdd (~35K wave-flushes/dir).
//            No LDS, 7812 waves/dir, 8-deep row-load pipeline.
// ---------------------------------------------------------------------------

#define NPB_LOG2 6
#define NPB 64             // destination nodes per bucket
#define MAXB 768           // max buckets supported by part_kernel LDS
#define PART_CHUNK 4096    // edges per block in part_kernel
#define SORT_CAP 12288     // max edges per bucket for bsort3 staging
#define CSCAN_CH 256       // edges per wave in cscan

__device__ __forceinline__ ushort f2bf(float f) {
    uint32_t u = __float_as_uint(f);
    return (ushort)((u + 0x7fffu + ((u >> 16) & 1u)) >> 16);  // RNE
}

__global__ void deg_kernel(const int* __restrict__ u, const int* __restrict__ s,
                           int E, int* __restrict__ udeg, int* __restrict__ sdeg) {
    int i = blockIdx.x * blockDim.x + threadIdx.x;
    int i4 = i * 4;
    if (i4 + 3 < E) {
        int4 a = *reinterpret_cast<const int4*>(u + i4);
        int4 b = *reinterpret_cast<const int4*>(s + i4);
        atomicAdd(&udeg[a.x], 1); atomicAdd(&udeg[a.y], 1);
        atomicAdd(&udeg[a.z], 1); atomicAdd(&udeg[a.w], 1);
        atomicAdd(&sdeg[b.x], 1); atomicAdd(&sdeg[b.y], 1);
        atomicAdd(&sdeg[b.z], 1); atomicAdd(&sdeg[b.w], 1);
    } else {
        for (int k = i4; k < E; ++k) {
            atomicAdd(&udeg[u[k]], 1);
            atomicAdd(&sdeg[s[k]], 1);
        }
    }
}

// Exclusive scan, single block of 1024 threads, 4 elems/thread per chunk.
__global__ __launch_bounds__(1024) void scan_kernel(const int* __restrict__ in,
                                                    int* __restrict__ out, int n) {
    __shared__ int ws[17];
    const int tid  = threadIdx.x;
    const int lane = tid & 63;
    const int wid  = tid >> 6;
    int carry = 0;  // meaningful on tid 0 only
    for (int base = 0; base < n; base += 4096) {
        int idx = base + tid * 4;
        int v0 = (idx + 0 < n) ? in[idx + 0] : 0;
        int v1 = (idx + 1 < n) ? in[idx + 1] : 0;
        int v2 = (idx + 2 < n) ? in[idx + 2] : 0;
        int v3 = (idx + 3 < n) ? in[idx + 3] : 0;
        int tsum = v0 + v1 + v2 + v3;
        int x = tsum;
#pragma unroll
        for (int d = 1; d < 64; d <<= 1) {
            int t = __shfl_up(x, d);
            if (lane >= d) x += t;
        }
        if (lane == 63) ws[wid] = x;
        __syncthreads();
        if (tid == 0) {
            int run = carry;
#pragma unroll
            for (int w = 0; w < 16; ++w) { int t = ws[w]; ws[w] = run; run += t; }
            carry = run;
        }
        __syncthreads();
        int excl = ws[wid] + (x - tsum);
        if (idx + 0 < n) out[idx + 0] = excl; excl += v0;
        if (idx + 1 < n) out[idx + 1] = excl; excl += v1;
        if (idx + 2 < n) out[idx + 2] = excl; excl += v2;
        if (idx + 3 < n) out[idx + 3] = excl;
        __syncthreads();
    }
    if (tid == 0) out[n] = carry;
}

__global__ void init_isd_kernel(const int* __restrict__ udeg, const int* __restrict__ sdeg,
                                float* __restrict__ isd_u, float* __restrict__ isd_s,
                                int n_user, int m_spot) {
    int i = blockIdx.x * blockDim.x + threadIdx.x;
    if (i < n_user) { int d = udeg[i]; isd_u[i] = d > 0 ? rsqrtf((float)d) : 0.f; }
    if (i < m_spot) { int d = sdeg[i]; isd_s[i] = d > 0 ? rsqrtf((float)d) : 0.f; }
}

// xb row layout is PERMUTED: slot 2c holds col c, slot 2c+1 holds col c+64,
// so a lane's uint32 load at byte row*256+4*l yields cols (l, l+64).
__global__ void convert_kernel(const float* __restrict__ x, const float* __restrict__ isd,
                               ushort* __restrict__ xb, int n_rows) {
    int idx = blockIdx.x * blockDim.x + threadIdx.x;
    if (idx >= (n_rows << 6)) return;
    int row = idx >> 6, c = idx & 63;
    float w = isd[row];
    const float* xr = x + ((size_t)row << 7);
    ushort2 o;
    o.x = f2bf(xr[c] * w);
    o.y = f2bf(xr[c + 64] * w);
    *reinterpret_cast<ushort2*>(xb + ((size_t)row << 7) + 2 * c) = o;
}

// Per-bucket degree totals: one wave per bucket (u buckets first, then s).
__global__ void breduce_kernel(const int* __restrict__ udeg, const int* __restrict__ sdeg,
                               int N, int M, int nbu, int nbs,
                               int* __restrict__ bdu, int* __restrict__ bds) {
    const int w = (blockIdx.x * blockDim.x + threadIdx.x) >> 6;
    const int lane = threadIdx.x & 63;
    if (w >= nbu + nbs) return;
    int v;
    if (w < nbu) {
        int i = (w << NPB_LOG2) + lane;
        v = (i < N) ? udeg[i] : 0;
    } else {
        int i = ((w - nbu) << NPB_LOG2) + lane;
        v = (i < M) ? sdeg[i] : 0;
    }
#pragma unroll
    for (int d = 32; d >= 1; d >>= 1) v += __shfl_down(v, d);
    if (lane == 0) {
        if (w < nbu) bdu[w] = v; else bds[w - nbu] = v;
    }
}

__global__ void gcur3_init_kernel(const int* __restrict__ buoff, const int* __restrict__ bsoff,
                                  int* __restrict__ gcu, int* __restrict__ gcs,
                                  int nbu, int nbs) {
    int i = blockIdx.x * blockDim.x + threadIdx.x;
    if (i < nbu) gcu[i] = buoff[i];
    if (i < nbs) gcs[i] = bsoff[i];
}

// Partition edges into NPB-node buckets of the primary (destination) index.
// LDS-staged so global writes are contiguous per-bucket runs.
__global__ __launch_bounds__(256) void part_kernel(
        const int* __restrict__ prim, const int* __restrict__ sec, int E,
        int nb, int* __restrict__ gcur, uint32_t* __restrict__ out) {
    __shared__ int hist[MAXB];
    __shared__ int loff[MAXB];
    __shared__ int gbase[MAXB];
    __shared__ int cur[MAXB];
    __shared__ int wsum[4];
    __shared__ uint32_t sbuf[PART_CHUNK];
    const int tid = threadIdx.x;
    const int lane = tid & 63;
    const int wid = tid >> 6;
    const int beg = blockIdx.x * PART_CHUNK;
    const int end = min(beg + PART_CHUNK, E);
    for (int b = tid; b < nb; b += 256) hist[b] = 0;
    __syncthreads();
    for (int i = beg + tid; i < end; i += 256)
        atomicAdd(&hist[prim[i] >> NPB_LOG2], 1);
    __syncthreads();
    // parallel exclusive scan of hist[0..nb) into loff (3 buckets per thread)
    {
        int b0 = tid * 3;
        int h0 = (b0 + 0 < nb) ? hist[b0 + 0] : 0;
        int h1 = (b0 + 1 < nb) ? hist[b0 + 1] : 0;
        int h2 = (b0 + 2 < nb) ? hist[b0 + 2] : 0;
        int tsum = h0 + h1 + h2;
        int x = tsum;
#pragma unroll
        for (int d = 1; d < 64; d <<= 1) {
            int t = __shfl_up(x, d);
            if (lane >= d) x += t;
        }
        if (lane == 63) wsum[wid] = x;
        __syncthreads();
        if (tid == 0) {
            int run = 0;
#pragma unroll
            for (int w = 0; w < 4; ++w) { int t = wsum[w]; wsum[w] = run; run += t; }
        }
        __syncthreads();
        int base = wsum[wid] + (x - tsum);
        if (b0 + 0 < nb) loff[b0 + 0] = base;
        if (b0 + 1 < nb) loff[b0 + 1] = base + h0;
        if (b0 + 2 < nb) loff[b0 + 2] = base + h0 + h1;
    }
    __syncthreads();
    for (int b = tid; b < nb; b += 256) {
        cur[b] = loff[b];
        int c = hist[b];
        gbase[b] = c > 0 ? atomicAdd(&gcur[b], c) : 0;
    }
    __syncthreads();
    for (int i = beg + tid; i < end; i += 256) {
        int p = prim[i], s = sec[i];
        int b = p >> NPB_LOG2;
        int l = atomicAdd(&cur[b], 1);
        sbuf[l] = ((uint32_t)p << 16) | (uint32_t)s;
    }
    __syncthreads();
    for (int b = wid; b < nb; b += 4) {
        int lo = loff[b], cnt = hist[b], gb = gbase[b];
        for (int k = lane; k < cnt; k += 64)
            out[gb + k] = sbuf[lo + k];
    }
}

// Counting sort of one bucket's segment by dst, in place (LDS-staged).
// Self-computes the 64-bin histogram; needs only bucket-level offsets.
// Perf-only: cscan is order-agnostic, so oversize buckets may be skipped.
__global__ __launch_bounds__(256) void bsort3_kernel(
        uint32_t* __restrict__ buf, const int* __restrict__ boff) {
    __shared__ uint32_t stage[SORT_CAP];
    __shared__ int hist[NPB];
    __shared__ int cur[NPB];
    const int tid = threadIdx.x;
    const int jbeg = boff[blockIdx.x];
    const int cnt = boff[blockIdx.x + 1] - jbeg;
    if (cnt > SORT_CAP) return;
    if (tid < NPB) hist[tid] = 0;
    __syncthreads();
    for (int k = tid; k < cnt; k += 256) {
        uint32_t p = buf[jbeg + k];
        stage[k] = p;
        atomicAdd(&hist[(p >> 16) & (NPB - 1)], 1);
    }
    __syncthreads();   // drains global reads before in-place overwrite
    if (tid < NPB) {   // wave 0: 64-wide exclusive scan via shfl
        int h = hist[tid];
        int x = h;
#pragma unroll
        for (int d = 1; d < 64; d <<= 1) {
            int t = __shfl_up(x, d);
            if (tid >= d) x += t;
        }
        cur[tid] = x - h;
    }
    __syncthreads();
    for (int k = tid; k < cnt; k += 256) {
        uint32_t p = stage[k];
        int slot = atomicAdd(&cur[(p >> 16) & (NPB - 1)], 1);
        buf[jbeg + slot] = p;
    }
}

// Wave per CSCAN_CH consecutive dst-sorted edges; register accumulate,
// flush on dst change via native f32 atomic. Order-agnostic correctness.
__global__ __launch_bounds__(256) void cscan_kernel(
        const ushort* __restrict__ xb, const uint32_t* __restrict__ packed, int E,
        const float* __restrict__ isd, float* __restrict__ out) {
    const int lane = threadIdx.x & 63;
    const int wave = (blockIdx.x << 2) + (threadIdx.x >> 6);
    const int base = wave * CSCAN_CH;
    if (base >= E) return;
    const int n = min(CSCAN_CH, E - base);
    const uint32_t* pp = packed + base;
    float ax = 0.f, ay = 0.f;
    int cur = (int)(pp[0] >> 16);

#define ROW(pv) (*reinterpret_cast<const uint32_t*>( \
        xb + (((size_t)((pv) & 0xffffu)) << 7) + (lane << 1)))
#define PROC(pv, rv) do {                                                  \
        int d_ = (int)((pv) >> 16);                                        \
        if (d_ != cur) {                                                   \
            float w_ = isd[cur];                                           \
            unsafeAtomicAdd(out + ((size_t)cur << 7) + lane, ax * w_);     \
            unsafeAtomicAdd(out + ((size_t)cur << 7) + 64 + lane, ay * w_);\
            ax = 0.f; ay = 0.f; cur = d_;                                  \
        }                                                                  \
        ax += __uint_as_float((rv) << 16);                                 \
        ay += __uint_as_float((rv) & 0xffff0000u);                         \
    } while (0)

    int k = 0;
    if (n >= 16) {
        uint4 Pa = *reinterpret_cast<const uint4*>(pp);
        uint4 Pb = *reinterpret_cast<const uint4*>(pp + 4);
        uint32_t r0 = ROW(Pa.x), r1 = ROW(Pa.y), r2 = ROW(Pa.z), r3 = ROW(Pa.w);
        uint32_t r4 = ROW(Pb.x), r5 = ROW(Pb.y), r6 = ROW(Pb.z), r7 = ROW(Pb.w);
        for (k = 8; k + 8 <= n; k += 8) {
            uint4 Na = *reinterpret_cast<const uint4*>(pp + k);
            uint4 Nb = *reinterpret_cast<const uint4*>(pp + k + 4);
            PROC(Pa.x, r0); PROC(Pa.y, r1); PROC(Pa.z, r2); PROC(Pa.w, r3);
            PROC(Pb.x, r4); PROC(Pb.y, r5); PROC(Pb.z, r6); PROC(Pb.w, r7);
            r0 = ROW(Na.x); r1 = ROW(Na.y); r2 = ROW(Na.z); r3 = ROW(Na.w);
            r4 = ROW(Nb.x); r5 = ROW(Nb.y); r6 = ROW(Nb.z); r7 = ROW(Nb.w);
            Pa = Na; Pb = Nb;
        }
        PROC(Pa.x, r0); PROC(Pa.y, r1); PROC(Pa.z, r2); PROC(Pa.w, r3);
        PROC(Pb.x, r4); PROC(Pb.y, r5); PROC(Pb.z, r6); PROC(Pb.w, r7);
    }
    for (; k < n; ++k) {
        uint32_t p = pp[k];
        uint32_t r = ROW(p);
        PROC(p, r);
    }
    float w = isd[cur];
    unsafeAtomicAdd(out + ((size_t)cur << 7) + lane, ax * w);
    unsafeAtomicAdd(out + ((size_t)cur << 7) + 64 + lane, ay * w);
#undef PROC
#undef ROW
}

// ---- fallback path kernels (round-2 proven CSR gather, f32 features) ------

__global__ void gcur_init_kernel(const int* __restrict__ uoff, const int* __restrict__ soff,
                                 int* __restrict__ gcur_u, int* __restrict__ gcur_s,
                                 int nbu, int nbs) {
    int i = blockIdx.x * blockDim.x + threadIdx.x;
    if (i < nbu) gcur_u[i] = uoff[i << NPB_LOG2];
    if (i < nbs) gcur_s[i] = soff[i << NPB_LOG2];
}

__global__ __launch_bounds__(256) void bsort_kernel(
        const uint32_t* __restrict__ packed, const int* __restrict__ noff,
        int nodes, int* __restrict__ csr) {
    __shared__ int cur[NPB];
    const int tid = threadIdx.x;
    const int ubase = blockIdx.x << NPB_LOG2;
    const int nin = min(NPB, nodes - ubase);
    if (tid < nin) cur[tid] = noff[ubase + tid];
    __syncthreads();
    const int jbeg = noff[ubase];
    const int jend = noff[ubase + nin];
    for (int j = jbeg + tid; j < jend; j += 256) {
        uint32_t p = packed[j];
        int local = (int)(p >> 16) - ubase;
        int slot = atomicAdd(&cur[local], 1);
        csr[slot] = (int)(p & 0xffffu);
    }
}

__global__ __launch_bounds__(256) void gather_kernel(const float* __restrict__ x_src,
                                                     const int* __restrict__ nbr,
                                                     const int* __restrict__ off,
                                                     const float* __restrict__ isd_dst,
                                                     const float* __restrict__ isd_src,
                                                     float* __restrict__ out, int n_rows) {
    const int lane = threadIdx.x & 63;
    const int row  = blockIdx.x * 4 + (threadIdx.x >> 6);
    if (row >= n_rows) return;
    const int jbeg = off[row];
    const int jend = off[row + 1];
    const float wd = isd_dst[row];
    float ax = 0.f, ay = 0.f;
    if (jbeg < jend) {
        int sidx = nbr[jbeg];
        for (int j = jbeg; j < jend; ++j) {
            int snext = (j + 1 < jend) ? nbr[j + 1] : 0;
            float w = wd * isd_src[sidx];
            const float2 v = *reinterpret_cast<const float2*>(x_src + (size_t)sidx * 128 + lane * 2);
            ax = fmaf(v.x, w, ax);
            ay = fmaf(v.y, w, ay);
            sidx = snext;
        }
    }
    float2 r; r.x = ax; r.y = ay;
    *reinterpret_cast<float2*>(out + (size_t)row * 128 + lane * 2) = r;
}

__global__ __launch_bounds__(256) void scatter_kernel(const float* __restrict__ spot_x,
                                                      const float* __restrict__ user_x,
                                                      const int* __restrict__ u,
                                                      const int* __restrict__ s, int E,
                                                      const float* __restrict__ isd_u,
                                                      const float* __restrict__ isd_s,
                                                      float* __restrict__ spot_out,
                                                      float* __restrict__ user_out) {
    const int lane = threadIdx.x & 63;
    const int e = blockIdx.x * 4 + (threadIdx.x >> 6);
    if (e >= E) return;
    const int uu = u[e], ss = s[e];
    const float w = isd_u[uu] * isd_s[ss];
    const float2 sv = *reinterpret_cast<const float2*>(spot_x + (size_t)ss * 128 + lane * 2);
    const float2 uv = *reinterpret_cast<const float2*>(user_x + (size_t)uu * 128 + lane * 2);
    atomicAdd(&user_out[(size_t)uu * 128 + lane * 2 + 0], sv.x * w);
    atomicAdd(&user_out[(size_t)uu * 128 + lane * 2 + 1], sv.y * w);
    atomicAdd(&spot_out[(size_t)ss * 128 + lane * 2 + 0], uv.x * w);
    atomicAdd(&spot_out[(size_t)ss * 128 + lane * 2 + 1], uv.y * w);
}

static inline char* align256(char* p) {
    return (char*)(((uintptr_t)p + 255u) & ~(uintptr_t)255u);
}

extern "C" void kernel_launch(void* const* d_in, const int* in_sizes, int n_in,
                              void* d_out, int out_size, void* d_ws, size_t ws_size,
                              hipStream_t stream) {
    const float* spot_x = (const float*)d_in[0];
    const float* user_x = (const float*)d_in[1];
    const int*   edges  = (const int*)d_in[2];
    const int M = in_sizes[0] / 128;   // spots
    const int N = in_sizes[1] / 128;   // users
    const int E = in_sizes[2] / 2;
    const int* u = edges;        // user_spot[0]
    const int* s = edges + E;    // user_spot[1]
    float* spot_out = (float*)d_out;
    float* user_out = (float*)d_out + (size_t)M * 128;

    const int nbu = (N + NPB - 1) / NPB;
    const int nbs = (M + NPB - 1) / NPB;

    // Workspace layout (fallback-critical arrays first), 256B-aligned slots.
    char* ws = (char*)d_ws;
    int*      udeg  = (int*)ws;  ws = align256(ws + sizeof(int) * (size_t)(N + M));
    int*      sdeg  = udeg + N;                         // contiguous with udeg for one memset
    float*    isd_u = (float*)ws; ws = align256(ws + sizeof(float) * N);
    float*    isd_s = (float*)ws; ws = align256(ws + sizeof(float) * M);
    size_t fallback_needed = (size_t)(ws - (char*)d_ws);
    int*      uoff  = (int*)ws;  ws = align256(ws + sizeof(int) * (size_t)(N + 1));
    int*      soff  = (int*)ws;  ws = align256(ws + sizeof(int) * (size_t)(M + 1));
    int*      bdu   = (int*)ws;  ws = align256(ws + sizeof(int) * (size_t)nbu);
    int*      bds   = (int*)ws;  ws = align256(ws + sizeof(int) * (size_t)nbs);
    int*      buoff = (int*)ws;  ws = align256(ws + sizeof(int) * (size_t)(nbu + 1));
    int*      bsoff = (int*)ws;  ws = align256(ws + sizeof(int) * (size_t)(nbs + 1));
    int*      gcu   = (int*)ws;  ws = align256(ws + sizeof(int) * (size_t)nbu);
    int*      gcs   = (int*)ws;  ws = align256(ws + sizeof(int) * (size_t)nbs);
    uint32_t* bufA  = (uint32_t*)ws; ws = align256(ws + sizeof(uint32_t) * (size_t)E);
    char* mark = ws;
    // union A (new path): bf16 pre-scaled feature tables
    ushort*   xbs   = (ushort*)mark;                    // spot features [M][128] permuted
    ushort*   xbu   = (ushort*)align256(mark + sizeof(ushort) * ((size_t)M * 128));
    size_t new_needed = (size_t)((char*)xbu - (char*)d_ws) + sizeof(ushort) * ((size_t)N * 128);
    // union B (old path): CSR neighbor buffer
    int*      bufB  = (int*)mark;
    size_t old_needed = (size_t)(mark - (char*)d_ws) + sizeof(int) * (size_t)E;

    hipMemsetAsync(udeg, 0, sizeof(int) * (size_t)(N + M), stream);
    deg_kernel<<<(E / 4 + 255) / 256, 256, 0, stream>>>(u, s, E, udeg, sdeg);
    const int nm = (N > M) ? N : M;
    init_isd_kernel<<<(nm + 255) / 256, 256, 0, stream>>>(udeg, sdeg, isd_u, isd_s, N, M);

    const int gpart = (E + PART_CHUNK - 1) / PART_CHUNK;
    if (new_needed <= ws_size && nbu <= MAXB && nbs <= MAXB) {
        convert_kernel<<<((M << 6) + 255) / 256, 256, 0, stream>>>(spot_x, isd_s, xbs, M);
        convert_kernel<<<((N << 6) + 255) / 256, 256, 0, stream>>>(user_x, isd_u, xbu, N);
        breduce_kernel<<<((nbu + nbs) * 64 + 255) / 256, 256, 0, stream>>>(
            udeg, sdeg, N, M, nbu, nbs, bdu, bds);
        scan_kernel<<<1, 1024, 0, stream>>>(bdu, buoff, nbu);
        scan_kernel<<<1, 1024, 0, stream>>>(bds, bsoff, nbs);
        gcur3_init_kernel<<<(nbs + 255) / 256, 256, 0, stream>>>(buoff, bsoff, gcu, gcs, nbu, nbs);
        hipMemsetAsync(d_out, 0, sizeof(float) * (size_t)out_size, stream);

        const int gscan = ((E + CSCAN_CH - 1) / CSCAN_CH + 3) / 4;
        // user direction: prim=u; accumulate spot rows into user_out
        part_kernel<<<gpart, 256, 0, stream>>>(u, s, E, nbu, gcu, bufA);
        bsort3_kernel<<<nbu, 256, 0, stream>>>(bufA, buoff);
        cscan_kernel<<<gscan, 256, 0, stream>>>(xbs, bufA, E, isd_u, user_out);
        // spot direction: prim=s; accumulate user rows into spot_out
        part_kernel<<<gpart, 256, 0, stream>>>(s, u, E, nbs, gcs, bufA);
        bsort3_kernel<<<nbs, 256, 0, stream>>>(bufA, bsoff);
        cscan_kernel<<<gscan, 256, 0, stream>>>(xbu, bufA, E, isd_s, spot_out);
    } else if (old_needed <= ws_size && nbu <= MAXB && nbs <= MAXB) {
        scan_kernel<<<1, 1024, 0, stream>>>(udeg, uoff, N);
        scan_kernel<<<1, 1024, 0, stream>>>(sdeg, soff, M);
        gcur_init_kernel<<<(nbs + 255) / 256, 256, 0, stream>>>(uoff, soff, gcu, gcs, nbu, nbs);
        part_kernel<<<gpart, 256, 0, stream>>>(u, s, E, nbu, gcu, bufA);
        bsort_kernel<<<nbu, 256, 0, stream>>>(bufA, uoff, N, bufB);
        gather_kernel<<<(N + 3) / 4, 256, 0, stream>>>(spot_x, bufB, uoff,
                                                       isd_u, isd_s, user_out, N);
        part_kernel<<<gpart, 256, 0, stream>>>(s, u, E, nbs, gcs, bufA);
        bsort_kernel<<<nbs, 256, 0, stream>>>(bufA, soff, M, bufB);
        gather_kernel<<<(M + 3) / 4, 256, 0, stream>>>(user_x, bufB, soff,
                                                       isd_s, isd_u, spot_out, M);
    } else if (fallback_needed <= ws_size) {
        hipMemsetAsync(d_out, 0, sizeof(float) * (size_t)out_size, stream);
        scatter_kernel<<<((size_t)E + 3) / 4, 256, 0, stream>>>(spot_x, user_x, u, s, E,
                                                                isd_u, isd_s, spot_out, user_out);
    }
}

// Round 5
// 296.316 us; speedup vs baseline: 11.5776x; 1.4455x over previous
//
#include <hip/hip_runtime.h>
#include <stdint.h>

// ---------------------------------------------------------------------------
// UserSpotConv: bipartite GCN aggregation.
//   user_out[u] = isd_u[u] * sum_{e: u_e=u} spot_x[s_e] * isd_s[s_e]
//   spot_out[s] = isd_s[s] * sum_{e: s_e=s} user_x[u_e] * isd_u[u_e]
// Round 5: kill deg_kernel (163 us; 4M memory-side atomics = 124 MB HBM
// write). Node degrees now come free from bsort3's per-bucket LDS histogram
// (writes isd there); bucket offsets come from bhist_kernel (LDS histogram
// over 1094 bucket bins, ~135K flush atomics instead of 4M).
// Pipeline: bhist -> scans -> part_u/part_s (2 edge buffers) -> bsort3 x2
// (sort + isd) -> convert_xbs -> cscan_u -> convert_xbu (union slot) -> cscan_s.
// ---------------------------------------------------------------------------

#define NPB_LOG2 6
#define NPB 64             // destination nodes per bucket
#define MAXB 768           // max buckets per direction
#define PART_CHUNK 8192    // edges per block in part_kernel
#define BH_CHUNK 16384     // edges per block in bhist_kernel
#define SORT_CAP 12288     // max edges per bucket for bsort3 staging
#define CSCAN_CH 256       // edges per wave in cscan

__device__ __forceinline__ ushort f2bf(float f) {
    uint32_t u = __float_as_uint(f);
    return (ushort)((u + 0x7fffu + ((u >> 16) & 1u)) >> 16);  // RNE
}

// Bucket-level histogram for BOTH directions in one pass. LDS-staged so the
// global atomic count is ~nb per block (not per edge).
__global__ __launch_bounds__(256) void bhist_kernel(
        const int* __restrict__ u, const int* __restrict__ s, int E,
        int nbu, int nbs, int* __restrict__ bd) {
    __shared__ int hist[2 * MAXB];
    const int tid = threadIdx.x;
    const int nb = nbu + nbs;
    const int beg = blockIdx.x * BH_CHUNK;
    const int end = min(beg + BH_CHUNK, E);
    for (int b = tid; b < nb; b += 256) hist[b] = 0;
    __syncthreads();
    for (int i = beg + tid; i < end; i += 256) {
        atomicAdd(&hist[u[i] >> NPB_LOG2], 1);
        atomicAdd(&hist[nbu + (s[i] >> NPB_LOG2)], 1);
    }
    __syncthreads();
    for (int b = tid; b < nb; b += 256) {
        int h = hist[b];
        if (h) atomicAdd(&bd[b], h);
    }
}

// Exclusive scan, single block of 1024 threads, 4 elems/thread per chunk.
__global__ __launch_bounds__(1024) void scan_kernel(const int* __restrict__ in,
                                                    int* __restrict__ out, int n) {
    __shared__ int ws[17];
    const int tid  = threadIdx.x;
    const int lane = tid & 63;
    const int wid  = tid >> 6;
    int carry = 0;  // meaningful on tid 0 only
    for (int base = 0; base < n; base += 4096) {
        int idx = base + tid * 4;
        int v0 = (idx + 0 < n) ? in[idx + 0] : 0;
        int v1 = (idx + 1 < n) ? in[idx + 1] : 0;
        int v2 = (idx + 2 < n) ? in[idx + 2] : 0;
        int v3 = (idx + 3 < n) ? in[idx + 3] : 0;
        int tsum = v0 + v1 + v2 + v3;
        int x = tsum;
#pragma unroll
        for (int d = 1; d < 64; d <<= 1) {
            int t = __shfl_up(x, d);
            if (lane >= d) x += t;
        }
        if (lane == 63) ws[wid] = x;
        __syncthreads();
        if (tid == 0) {
            int run = carry;
#pragma unroll
            for (int w = 0; w < 16; ++w) { int t = ws[w]; ws[w] = run; run += t; }
            carry = run;
        }
        __syncthreads();
        int excl = ws[wid] + (x - tsum);
        if (idx + 0 < n) out[idx + 0] = excl; excl += v0;
        if (idx + 1 < n) out[idx + 1] = excl; excl += v1;
        if (idx + 2 < n) out[idx + 2] = excl; excl += v2;
        if (idx + 3 < n) out[idx + 3] = excl;
        __syncthreads();
    }
    if (tid == 0) out[n] = carry;
}

__global__ void gcur3_init_kernel(const int* __restrict__ buoff, const int* __restrict__ bsoff,
                                  int* __restrict__ gcu, int* __restrict__ gcs,
                                  int nbu, int nbs) {
    int i = blockIdx.x * blockDim.x + threadIdx.x;
    if (i < nbu) gcu[i] = buoff[i];
    if (i < nbs) gcs[i] = bsoff[i];
}

// xb row layout is PERMUTED: slot 2c holds col c, slot 2c+1 holds col c+64,
// so a lane's uint32 load at byte row*256+4*l yields cols (l, l+64).
__global__ void convert_kernel(const float* __restrict__ x, const float* __restrict__ isd,
                               ushort* __restrict__ xb, int n_rows) {
    int idx = blockIdx.x * blockDim.x + threadIdx.x;
    if (idx >= (n_rows << 6)) return;
    int row = idx >> 6, c = idx & 63;
    float w = isd[row];
    const float* xr = x + ((size_t)row << 7);
    ushort2 o;
    o.x = f2bf(xr[c] * w);
    o.y = f2bf(xr[c + 64] * w);
    *reinterpret_cast<ushort2*>(xb + ((size_t)row << 7) + 2 * c) = o;
}

// Partition edges into NPB-node buckets of the primary (destination) index.
// LDS-staged so global writes are contiguous per-bucket runs.
__global__ __launch_bounds__(256) void part_kernel(
        const int* __restrict__ prim, const int* __restrict__ sec, int E,
        int nb, int* __restrict__ gcur, uint32_t* __restrict__ out) {
    __shared__ int hist[MAXB];
    __shared__ int loff[MAXB];
    __shared__ int gbase[MAXB];
    __shared__ int cur[MAXB];
    __shared__ int wsum[4];
    __shared__ uint32_t sbuf[PART_CHUNK];
    const int tid = threadIdx.x;
    const int lane = tid & 63;
    const int wid = tid >> 6;
    const int beg = blockIdx.x * PART_CHUNK;
    const int end = min(beg + PART_CHUNK, E);
    for (int b = tid; b < nb; b += 256) hist[b] = 0;
    __syncthreads();
    for (int i = beg + tid; i < end; i += 256)
        atomicAdd(&hist[prim[i] >> NPB_LOG2], 1);
    __syncthreads();
    // parallel exclusive scan of hist[0..nb) into loff (3 buckets per thread)
    {
        int b0 = tid * 3;
        int h0 = (b0 + 0 < nb) ? hist[b0 + 0] : 0;
        int h1 = (b0 + 1 < nb) ? hist[b0 + 1] : 0;
        int h2 = (b0 + 2 < nb) ? hist[b0 + 2] : 0;
        int tsum = h0 + h1 + h2;
        int x = tsum;
#pragma unroll
        for (int d = 1; d < 64; d <<= 1) {
            int t = __shfl_up(x, d);
            if (lane >= d) x += t;
        }
        if (lane == 63) wsum[wid] = x;
        __syncthreads();
        if (tid == 0) {
            int run = 0;
#pragma unroll
            for (int w = 0; w < 4; ++w) { int t = wsum[w]; wsum[w] = run; run += t; }
        }
        __syncthreads();
        int base = wsum[wid] + (x - tsum);
        if (b0 + 0 < nb) loff[b0 + 0] = base;
        if (b0 + 1 < nb) loff[b0 + 1] = base + h0;
        if (b0 + 2 < nb) loff[b0 + 2] = base + h0 + h1;
    }
    __syncthreads();
    for (int b = tid; b < nb; b += 256) {
        cur[b] = loff[b];
        int c = hist[b];
        gbase[b] = c > 0 ? atomicAdd(&gcur[b], c) : 0;
    }
    __syncthreads();
    for (int i = beg + tid; i < end; i += 256) {
        int p = prim[i], s = sec[i];
        int b = p >> NPB_LOG2;
        int l = atomicAdd(&cur[b], 1);
        sbuf[l] = ((uint32_t)p << 16) | (uint32_t)s;
    }
    __syncthreads();
    for (int b = wid; b < nb; b += 4) {
        int lo = loff[b], cnt = hist[b], gb = gbase[b];
        for (int k = lane; k < cnt; k += 64)
            out[gb + k] = sbuf[lo + k];
    }
}

// Counting sort of one bucket's segment by dst, in place (LDS-staged), AND
// write isd[node] = rsqrt(degree) from the self-computed histogram (every
// edge of node d is in bucket d>>6, so hist = full degree).
__global__ __launch_bounds__(256) void bsort3_kernel(
        uint32_t* __restrict__ buf, const int* __restrict__ boff,
        float* __restrict__ isd, int n_rows) {
    __shared__ uint32_t stage[SORT_CAP];
    __shared__ int hist[NPB];
    __shared__ int cur[NPB];
    const int tid = threadIdx.x;
    const int jbeg = boff[blockIdx.x];
    const int cnt = boff[blockIdx.x + 1] - jbeg;
    const bool fits = (cnt <= SORT_CAP);   // sort is perf-only; isd always written
    if (tid < NPB) hist[tid] = 0;
    __syncthreads();
    for (int k = tid; k < cnt; k += 256) {
        uint32_t p = buf[jbeg + k];
        if (fits) stage[k] = p;
        atomicAdd(&hist[(p >> 16) & (NPB - 1)], 1);
    }
    __syncthreads();   // drains global reads before in-place overwrite
    if (tid < NPB) {   // wave 0: 64-wide exclusive scan via shfl + isd write
        int h = hist[tid];
        int x = h;
#pragma unroll
        for (int d = 1; d < 64; d <<= 1) {
            int t = __shfl_up(x, d);
            if (tid >= d) x += t;
        }
        cur[tid] = x - h;
        int node = (blockIdx.x << NPB_LOG2) + tid;
        if (node < n_rows) isd[node] = h > 0 ? rsqrtf((float)h) : 0.f;
    }
    __syncthreads();
    if (fits) {
        for (int k = tid; k < cnt; k += 256) {
            uint32_t p = stage[k];
            int slot = atomicAdd(&cur[(p >> 16) & (NPB - 1)], 1);
            buf[jbeg + slot] = p;
        }
    }
}

// Wave per CSCAN_CH consecutive dst-sorted edges; register accumulate,
// flush on dst change via native f32 atomic. Order-agnostic correctness.
__global__ __launch_bounds__(256) void cscan_kernel(
        const ushort* __restrict__ xb, const uint32_t* __restrict__ packed, int E,
        const float* __restrict__ isd, float* __restrict__ out) {
    const int lane = threadIdx.x & 63;
    const int wave = (blockIdx.x << 2) + (threadIdx.x >> 6);
    const int base = wave * CSCAN_CH;
    if (base >= E) return;
    const int n = min(CSCAN_CH, E - base);
    const uint32_t* pp = packed + base;
    float ax = 0.f, ay = 0.f;
    int cur = (int)(pp[0] >> 16);

#define ROW(pv) (*reinterpret_cast<const uint32_t*>( \
        xb + (((size_t)((pv) & 0xffffu)) << 7) + (lane << 1)))
#define PROC(pv, rv) do {                                                  \
        int d_ = (int)((pv) >> 16);                                        \
        if (d_ != cur) {                                                   \
            float w_ = isd[cur];                                           \
            unsafeAtomicAdd(out + ((size_t)cur << 7) + lane, ax * w_);     \
            unsafeAtomicAdd(out + ((size_t)cur << 7) + 64 + lane, ay * w_);\
            ax = 0.f; ay = 0.f; cur = d_;                                  \
        }                                                                  \
        ax += __uint_as_float((rv) << 16);                                 \
        ay += __uint_as_float((rv) & 0xffff0000u);                         \
    } while (0)

    int k = 0;
    if (n >= 16) {
        uint4 Pa = *reinterpret_cast<const uint4*>(pp);
        uint4 Pb = *reinterpret_cast<const uint4*>(pp + 4);
        uint32_t r0 = ROW(Pa.x), r1 = ROW(Pa.y), r2 = ROW(Pa.z), r3 = ROW(Pa.w);
        uint32_t r4 = ROW(Pb.x), r5 = ROW(Pb.y), r6 = ROW(Pb.z), r7 = ROW(Pb.w);
        for (k = 8; k + 8 <= n; k += 8) {
            uint4 Na = *reinterpret_cast<const uint4*>(pp + k);
            uint4 Nb = *reinterpret_cast<const uint4*>(pp + k + 4);
            PROC(Pa.x, r0); PROC(Pa.y, r1); PROC(Pa.z, r2); PROC(Pa.w, r3);
            PROC(Pb.x, r4); PROC(Pb.y, r5); PROC(Pb.z, r6); PROC(Pb.w, r7);
            r0 = ROW(Na.x); r1 = ROW(Na.y); r2 = ROW(Na.z); r3 = ROW(Na.w);
            r4 = ROW(Nb.x); r5 = ROW(Nb.y); r6 = ROW(Nb.z); r7 = ROW(Nb.w);
            Pa = Na; Pb = Nb;
        }
        PROC(Pa.x, r0); PROC(Pa.y, r1); PROC(Pa.z, r2); PROC(Pa.w, r3);
        PROC(Pb.x, r4); PROC(Pb.y, r5); PROC(Pb.z, r6); PROC(Pb.w, r7);
    }
    for (; k < n; ++k) {
        uint32_t p = pp[k];
        uint32_t r = ROW(p);
        PROC(p, r);
    }
    float w = isd[cur];
    unsafeAtomicAdd(out + ((size_t)cur << 7) + lane, ax * w);
    unsafeAtomicAdd(out + ((size_t)cur << 7) + 64 + lane, ay * w);
#undef PROC
#undef ROW
}

// ---- fallback-path kernels (rounds 2/4 proven) ----------------------------

__global__ void deg_kernel(const int* __restrict__ u, const int* __restrict__ s,
                           int E, int* __restrict__ udeg, int* __restrict__ sdeg) {
    int i = blockIdx.x * blockDim.x + threadIdx.x;
    int i4 = i * 4;
    if (i4 + 3 < E) {
        int4 a = *reinterpret_cast<const int4*>(u + i4);
        int4 b = *reinterpret_cast<const int4*>(s + i4);
        atomicAdd(&udeg[a.x], 1); atomicAdd(&udeg[a.y], 1);
        atomicAdd(&udeg[a.z], 1); atomicAdd(&udeg[a.w], 1);
        atomicAdd(&sdeg[b.x], 1); atomicAdd(&sdeg[b.y], 1);
        atomicAdd(&sdeg[b.z], 1); atomicAdd(&sdeg[b.w], 1);
    } else {
        for (int k = i4; k < E; ++k) {
            atomicAdd(&udeg[u[k]], 1);
            atomicAdd(&sdeg[s[k]], 1);
        }
    }
}

__global__ void init_isd_kernel(const int* __restrict__ udeg, const int* __restrict__ sdeg,
                                float* __restrict__ isd_u, float* __restrict__ isd_s,
                                int n_user, int m_spot) {
    int i = blockIdx.x * blockDim.x + threadIdx.x;
    if (i < n_user) { int d = udeg[i]; isd_u[i] = d > 0 ? rsqrtf((float)d) : 0.f; }
    if (i < m_spot) { int d = sdeg[i]; isd_s[i] = d > 0 ? rsqrtf((float)d) : 0.f; }
}

__global__ void breduce_kernel(const int* __restrict__ udeg, const int* __restrict__ sdeg,
                               int N, int M, int nbu, int nbs,
                               int* __restrict__ bdu, int* __restrict__ bds) {
    const int w = (blockIdx.x * blockDim.x + threadIdx.x) >> 6;
    const int lane = threadIdx.x & 63;
    if (w >= nbu + nbs) return;
    int v;
    if (w < nbu) {
        int i = (w << NPB_LOG2) + lane;
        v = (i < N) ? udeg[i] : 0;
    } else {
        int i = ((w - nbu) << NPB_LOG2) + lane;
        v = (i < M) ? sdeg[i] : 0;
    }
#pragma unroll
    for (int d = 32; d >= 1; d >>= 1) v += __shfl_down(v, d);
    if (lane == 0) {
        if (w < nbu) bdu[w] = v; else bds[w - nbu] = v;
    }
}

__global__ void gcur_init_kernel(const int* __restrict__ uoff, const int* __restrict__ soff,
                                 int* __restrict__ gcur_u, int* __restrict__ gcur_s,
                                 int nbu, int nbs) {
    int i = blockIdx.x * blockDim.x + threadIdx.x;
    if (i < nbu) gcur_u[i] = uoff[i << NPB_LOG2];
    if (i < nbs) gcur_s[i] = soff[i << NPB_LOG2];
}

__global__ __launch_bounds__(256) void bsort_kernel(
        const uint32_t* __restrict__ packed, const int* __restrict__ noff,
        int nodes, int* __restrict__ csr) {
    __shared__ int cur[NPB];
    const int tid = threadIdx.x;
    const int ubase = blockIdx.x << NPB_LOG2;
    const int nin = min(NPB, nodes - ubase);
    if (tid < nin) cur[tid] = noff[ubase + tid];
    __syncthreads();
    const int jbeg = noff[ubase];
    const int jend = noff[ubase + nin];
    for (int j = jbeg + tid; j < jend; j += 256) {
        uint32_t p = packed[j];
        int local = (int)(p >> 16) - ubase;
        int slot = atomicAdd(&cur[local], 1);
        csr[slot] = (int)(p & 0xffffu);
    }
}

__global__ __launch_bounds__(256) void gather_kernel(const float* __restrict__ x_src,
                                                     const int* __restrict__ nbr,
                                                     const int* __restrict__ off,
                                                     const float* __restrict__ isd_dst,
                                                     const float* __restrict__ isd_src,
                                                     float* __restrict__ out, int n_rows) {
    const int lane = threadIdx.x & 63;
    const int row  = blockIdx.x * 4 + (threadIdx.x >> 6);
    if (row >= n_rows) return;
    const int jbeg = off[row];
    const int jend = off[row + 1];
    const float wd = isd_dst[row];
    float ax = 0.f, ay = 0.f;
    if (jbeg < jend) {
        int sidx = nbr[jbeg];
        for (int j = jbeg; j < jend; ++j) {
            int snext = (j + 1 < jend) ? nbr[j + 1] : 0;
            float w = wd * isd_src[sidx];
            const float2 v = *reinterpret_cast<const float2*>(x_src + (size_t)sidx * 128 + lane * 2);
            ax = fmaf(v.x, w, ax);
            ay = fmaf(v.y, w, ay);
            sidx = snext;
        }
    }
    float2 r; r.x = ax; r.y = ay;
    *reinterpret_cast<float2*>(out + (size_t)row * 128 + lane * 2) = r;
}

__global__ __launch_bounds__(256) void scatter_kernel(const float* __restrict__ spot_x,
                                                      const float* __restrict__ user_x,
                                                      const int* __restrict__ u,
                                                      const int* __restrict__ s, int E,
                                                      const float* __restrict__ isd_u,
                                                      const float* __restrict__ isd_s,
                                                      float* __restrict__ spot_out,
                                                      float* __restrict__ user_out) {
    const int lane = threadIdx.x & 63;
    const int e = blockIdx.x * 4 + (threadIdx.x >> 6);
    if (e >= E) return;
    const int uu = u[e], ss = s[e];
    const float w = isd_u[uu] * isd_s[ss];
    const float2 sv = *reinterpret_cast<const float2*>(spot_x + (size_t)ss * 128 + lane * 2);
    const float2 uv = *reinterpret_cast<const float2*>(user_x + (size_t)uu * 128 + lane * 2);
    atomicAdd(&user_out[(size_t)uu * 128 + lane * 2 + 0], sv.x * w);
    atomicAdd(&user_out[(size_t)uu * 128 + lane * 2 + 1], sv.y * w);
    atomicAdd(&spot_out[(size_t)ss * 128 + lane * 2 + 0], uv.x * w);
    atomicAdd(&spot_out[(size_t)ss * 128 + lane * 2 + 1], uv.y * w);
}

static inline char* align256(char* p) {
    return (char*)(((uintptr_t)p + 255u) & ~(uintptr_t)255u);
}

extern "C" void kernel_launch(void* const* d_in, const int* in_sizes, int n_in,
                              void* d_out, int out_size, void* d_ws, size_t ws_size,
                              hipStream_t stream) {
    const float* spot_x = (const float*)d_in[0];
    const float* user_x = (const float*)d_in[1];
    const int*   edges  = (const int*)d_in[2];
    const int M = in_sizes[0] / 128;   // spots
    const int N = in_sizes[1] / 128;   // users
    const int E = in_sizes[2] / 2;
    const int* u = edges;        // user_spot[0]
    const int* s = edges + E;    // user_spot[1]
    float* spot_out = (float*)d_out;
    float* user_out = (float*)d_out + (size_t)M * 128;

    const int nbu = (N + NPB - 1) / NPB;
    const int nbs = (M + NPB - 1) / NPB;
    const int nm = (N > M) ? N : M;
    const int gpart = (E + PART_CHUNK - 1) / PART_CHUNK;
    const int gscan = ((E + CSCAN_CH - 1) / CSCAN_CH + 3) / 4;

    // ---------------- fast-path layout (deg-free, 2 edge buffers) ----------
    {
        char* ws = (char*)d_ws;
        float*    isd_u = (float*)ws; ws = align256(ws + sizeof(float) * (size_t)N);
        float*    isd_s = (float*)ws; ws = align256(ws + sizeof(float) * (size_t)M);
        int*      bd    = (int*)ws;   ws = align256(ws + sizeof(int) * (size_t)(nbu + nbs));
        int*      buoff = (int*)ws;   ws = align256(ws + sizeof(int) * (size_t)(nbu + 1));
        int*      bsoff = (int*)ws;   ws = align256(ws + sizeof(int) * (size_t)(nbs + 1));
        int*      gcu   = (int*)ws;   ws = align256(ws + sizeof(int) * (size_t)nbu);
        int*      gcs   = (int*)ws;   ws = align256(ws + sizeof(int) * (size_t)nbs);
        uint32_t* bufU  = (uint32_t*)ws; ws = align256(ws + sizeof(uint32_t) * (size_t)E);
        uint32_t* bufS  = (uint32_t*)ws; ws = align256(ws + sizeof(uint32_t) * (size_t)E);
        ushort*   xb    = (ushort*)ws;   // union: spot table, then user table
        size_t fast_needed = (size_t)(ws - (char*)d_ws) + sizeof(ushort) * ((size_t)nm * 128);

        if (fast_needed <= ws_size && nbu <= MAXB && nbs <= MAXB) {
            hipMemsetAsync(bd, 0, sizeof(int) * (size_t)(nbu + nbs), stream);
            hipMemsetAsync(d_out, 0, sizeof(float) * (size_t)out_size, stream);
            bhist_kernel<<<(E + BH_CHUNK - 1) / BH_CHUNK, 256, 0, stream>>>(
                u, s, E, nbu, nbs, bd);
            scan_kernel<<<1, 1024, 0, stream>>>(bd, buoff, nbu);
            scan_kernel<<<1, 1024, 0, stream>>>(bd + nbu, bsoff, nbs);
            gcur3_init_kernel<<<(nbs + nbu + 255) / 256, 256, 0, stream>>>(
                buoff, bsoff, gcu, gcs, nbu, nbs);
            part_kernel<<<gpart, 256, 0, stream>>>(u, s, E, nbu, gcu, bufU);
            part_kernel<<<gpart, 256, 0, stream>>>(s, u, E, nbs, gcs, bufS);
            bsort3_kernel<<<nbu, 256, 0, stream>>>(bufU, buoff, isd_u, N);
            bsort3_kernel<<<nbs, 256, 0, stream>>>(bufS, bsoff, isd_s, M);
            // user direction: spot table scaled by isd_s, flush by isd_u
            convert_kernel<<<((M << 6) + 255) / 256, 256, 0, stream>>>(spot_x, isd_s, xb, M);
            cscan_kernel<<<gscan, 256, 0, stream>>>(xb, bufU, E, isd_u, user_out);
            // spot direction: user table (same union slot) scaled by isd_u
            convert_kernel<<<((N << 6) + 255) / 256, 256, 0, stream>>>(user_x, isd_u, xb, N);
            cscan_kernel<<<gscan, 256, 0, stream>>>(xb, bufS, E, isd_s, spot_out);
            return;
        }
    }

    // ---------------- fallback layouts (round-4 proven) --------------------
    char* ws = (char*)d_ws;
    int*      udeg  = (int*)ws;  ws = align256(ws + sizeof(int) * (size_t)(N + M));
    int*      sdeg  = udeg + N;
    float*    isd_u = (float*)ws; ws = align256(ws + sizeof(float) * (size_t)N);
    float*    isd_s = (float*)ws; ws = align256(ws + sizeof(float) * (size_t)M);
    size_t fallback_needed = (size_t)(ws - (char*)d_ws);
    int*      uoff  = (int*)ws;  ws = align256(ws + sizeof(int) * (size_t)(N + 1));
    int*      soff  = (int*)ws;  ws = align256(ws + sizeof(int) * (size_t)(M + 1));
    int*      bdu   = (int*)ws;  ws = align256(ws + sizeof(int) * (size_t)nbu);
    int*      bds   = (int*)ws;  ws = align256(ws + sizeof(int) * (size_t)nbs);
    int*      buoff = (int*)ws;  ws = align256(ws + sizeof(int) * (size_t)(nbu + 1));
    int*      bsoff = (int*)ws;  ws = align256(ws + sizeof(int) * (size_t)(nbs + 1));
    int*      gcu   = (int*)ws;  ws = align256(ws + sizeof(int) * (size_t)nbu);
    int*      gcs   = (int*)ws;  ws = align256(ws + sizeof(int) * (size_t)nbs);
    uint32_t* bufA  = (uint32_t*)ws; ws = align256(ws + sizeof(uint32_t) * (size_t)E);
    char* mark = ws;
    ushort*   xbs   = (ushort*)mark;
    ushort*   xbu   = (ushort*)align256(mark + sizeof(ushort) * ((size_t)M * 128));
    size_t new_needed = (size_t)((char*)xbu - (char*)d_ws) + sizeof(ushort) * ((size_t)N * 128);
    int*      bufB  = (int*)mark;
    size_t old_needed = (size_t)(mark - (char*)d_ws) + sizeof(int) * (size_t)E;

    hipMemsetAsync(udeg, 0, sizeof(int) * (size_t)(N + M), stream);
    deg_kernel<<<(E / 4 + 255) / 256, 256, 0, stream>>>(u, s, E, udeg, sdeg);
    init_isd_kernel<<<(nm + 255) / 256, 256, 0, stream>>>(udeg, sdeg, isd_u, isd_s, N, M);

    if (new_needed <= ws_size && nbu <= MAXB && nbs <= MAXB) {
        convert_kernel<<<((M << 6) + 255) / 256, 256, 0, stream>>>(spot_x, isd_s, xbs, M);
        convert_kernel<<<((N << 6) + 255) / 256, 256, 0, stream>>>(user_x, isd_u, xbu, N);
        breduce_kernel<<<((nbu + nbs) * 64 + 255) / 256, 256, 0, stream>>>(
            udeg, sdeg, N, M, nbu, nbs, bdu, bds);
        scan_kernel<<<1, 1024, 0, stream>>>(bdu, buoff, nbu);
        scan_kernel<<<1, 1024, 0, stream>>>(bds, bsoff, nbs);
        gcur3_init_kernel<<<(nbs + nbu + 255) / 256, 256, 0, stream>>>(
            buoff, bsoff, gcu, gcs, nbu, nbs);
        hipMemsetAsync(d_out, 0, sizeof(float) * (size_t)out_size, stream);
        part_kernel<<<gpart, 256, 0, stream>>>(u, s, E, nbu, gcu, bufA);
        bsort3_kernel<<<nbu, 256, 0, stream>>>(bufA, buoff, isd_u, N);   // re-writes same isd
        cscan_kernel<<<gscan, 256, 0, stream>>>(xbs, bufA, E, isd_u, user_out);
        part_kernel<<<gpart, 256, 0, stream>>>(s, u, E, nbs, gcs, bufA);
        bsort3_kernel<<<nbs, 256, 0, stream>>>(bufA, bsoff, isd_s, M);
        cscan_kernel<<<gscan, 256, 0, stream>>>(xbu, bufA, E, isd_s, spot_out);
    } else if (old_needed <= ws_size && nbu <= MAXB && nbs <= MAXB) {
        scan_kernel<<<1, 1024, 0, stream>>>(udeg, uoff, N);
        scan_kernel<<<1, 1024, 0, stream>>>(sdeg, soff, M);
        gcur_init_kernel<<<(nbs + nbu + 255) / 256, 256, 0, stream>>>(uoff, soff, gcu, gcs, nbu, nbs);
        part_kernel<<<gpart, 256, 0, stream>>>(u, s, E, nbu, gcu, bufA);
        bsort_kernel<<<nbu, 256, 0, stream>>>(bufA, uoff, N, bufB);
        gather_kernel<<<(N + 3) / 4, 256, 0, stream>>>(spot_x, bufB, uoff,
                                                       isd_u, isd_s, user_out, N);
        part_kernel<<<gpart, 256, 0, stream>>>(s, u, E, nbs, gcs, bufA);
        bsort_kernel<<<nbs, 256, 0, stream>>>(bufA, soff, M, bufB);
        gather_kernel<<<(M + 3) / 4, 256, 0, stream>>>(user_x, bufB, soff,
                                                       isd_s, isd_u, spot_out, M);
    } else if (fallback_needed <= ws_size) {
        hipMemsetAsync(d_out, 0, sizeof(float) * (size_t)out_size, stream);
        scatter_kernel<<<((size_t)E + 3) / 4, 256, 0, stream>>>(spot_x, user_x, u, s, E,
                                                                isd_u, isd_s, spot_out, user_out);
    }
}

// Round 6
// 290.264 us; speedup vs baseline: 11.8190x; 1.0209x over previous
//
#include <hip/hip_runtime.h>
#include <stdint.h>

// ---------------------------------------------------------------------------
// UserSpotConv: bipartite GCN aggregation.
//   user_out[u] = isd_u[u] * sum_{e: u_e=u} spot_x[s_e] * isd_s[s_e]
//   spot_out[s] = isd_s[s] * sum_{e: s_e=s} user_x[u_e] * isd_u[u_e]
// Round 6: cscan was latency-exposed (53% VALUBusy, rows issued AFTER the
// consuming PROC of the previous group). Rewrite: software-pipelined —
// rows for group g+1 issued BEFORE PROC(g), packed 2 groups ahead (~200cy
// cover), plus a wave-uniform "whole group same dst" add-tree fast path
// (runs avg 47-74 edges -> ~80% of 8-groups uniform). scan+gcur fused.
// ---------------------------------------------------------------------------

#define NPB_LOG2 6
#define NPB 64             // destination nodes per bucket
#define MAXB 768           // max buckets per direction
#define PART_CHUNK 8192    // edges per block in part_kernel
#define BH_CHUNK 16384     // edges per block in bhist_kernel
#define SORT_CAP 12288     // max edges per bucket for bsort3 staging
#define CSCAN_CH 256       // edges per wave in cscan

__device__ __forceinline__ ushort f2bf(float f) {
    uint32_t u = __float_as_uint(f);
    return (ushort)((u + 0x7fffu + ((u >> 16) & 1u)) >> 16);  // RNE
}

// Bucket-level histogram for BOTH directions in one pass. LDS-staged so the
// global atomic count is ~nb per block (not per edge).
__global__ __launch_bounds__(256) void bhist_kernel(
        const int* __restrict__ u, const int* __restrict__ s, int E,
        int nbu, int nbs, int* __restrict__ bd) {
    __shared__ int hist[2 * MAXB];
    const int tid = threadIdx.x;
    const int nb = nbu + nbs;
    const int beg = blockIdx.x * BH_CHUNK;
    const int end = min(beg + BH_CHUNK, E);
    for (int b = tid; b < nb; b += 256) hist[b] = 0;
    __syncthreads();
    for (int i = beg + tid; i < end; i += 256) {
        atomicAdd(&hist[u[i] >> NPB_LOG2], 1);
        atomicAdd(&hist[nbu + (s[i] >> NPB_LOG2)], 1);
    }
    __syncthreads();
    for (int b = tid; b < nb; b += 256) {
        int h = hist[b];
        if (h) atomicAdd(&bd[b], h);
    }
}

// Fused dual exclusive scan (block 0: u-buckets, block 1: s-buckets) that
// also initializes the part_kernel global cursors. n <= 1024 (MAXB=768).
__global__ __launch_bounds__(1024) void scan2_kernel(
        const int* __restrict__ bd, int nbu, int nbs,
        int* __restrict__ buoff, int* __restrict__ bsoff,
        int* __restrict__ gcu, int* __restrict__ gcs) {
    __shared__ int wsums[16];
    __shared__ int total;
    const int tid = threadIdx.x, lane = tid & 63, wid = tid >> 6;
    const int n   = blockIdx.x ? nbs : nbu;
    const int* in = blockIdx.x ? (bd + nbu) : bd;
    int* out = blockIdx.x ? bsoff : buoff;
    int* gc  = blockIdx.x ? gcs   : gcu;
    int v = (tid < n) ? in[tid] : 0;
    int x = v;
#pragma unroll
    for (int d = 1; d < 64; d <<= 1) {
        int t = __shfl_up(x, d);
        if (lane >= d) x += t;
    }
    if (lane == 63) wsums[wid] = x;
    __syncthreads();
    if (tid == 0) {
        int run = 0;
#pragma unroll
        for (int w = 0; w < 16; ++w) { int t = wsums[w]; wsums[w] = run; run += t; }
        total = run;
    }
    __syncthreads();
    int excl = wsums[wid] + (x - v);
    if (tid < n) { out[tid] = excl; gc[tid] = excl; }
    if (tid == 0) out[n] = total;
}

// xb row layout is PERMUTED: slot 2c holds col c, slot 2c+1 holds col c+64,
// so a lane's uint32 load at byte row*256+4*l yields cols (l, l+64).
__global__ void convert_kernel(const float* __restrict__ x, const float* __restrict__ isd,
                               ushort* __restrict__ xb, int n_rows) {
    int idx = blockIdx.x * blockDim.x + threadIdx.x;
    if (idx >= (n_rows << 6)) return;
    int row = idx >> 6, c = idx & 63;
    float w = isd[row];
    const float* xr = x + ((size_t)row << 7);
    ushort2 o;
    o.x = f2bf(xr[c] * w);
    o.y = f2bf(xr[c + 64] * w);
    *reinterpret_cast<ushort2*>(xb + ((size_t)row << 7) + 2 * c) = o;
}

// Partition edges into NPB-node buckets of the primary (destination) index.
// LDS-staged so global writes are contiguous per-bucket runs.
__global__ __launch_bounds__(256) void part_kernel(
        const int* __restrict__ prim, const int* __restrict__ sec, int E,
        int nb, int* __restrict__ gcur, uint32_t* __restrict__ out) {
    __shared__ int hist[MAXB];
    __shared__ int loff[MAXB];
    __shared__ int gbase[MAXB];
    __shared__ int cur[MAXB];
    __shared__ int wsum[4];
    __shared__ uint32_t sbuf[PART_CHUNK];
    const int tid = threadIdx.x;
    const int lane = tid & 63;
    const int wid = tid >> 6;
    const int beg = blockIdx.x * PART_CHUNK;
    const int end = min(beg + PART_CHUNK, E);
    for (int b = tid; b < nb; b += 256) hist[b] = 0;
    __syncthreads();
    for (int i = beg + tid; i < end; i += 256)
        atomicAdd(&hist[prim[i] >> NPB_LOG2], 1);
    __syncthreads();
    // parallel exclusive scan of hist[0..nb) into loff (3 buckets per thread)
    {
        int b0 = tid * 3;
        int h0 = (b0 + 0 < nb) ? hist[b0 + 0] : 0;
        int h1 = (b0 + 1 < nb) ? hist[b0 + 1] : 0;
        int h2 = (b0 + 2 < nb) ? hist[b0 + 2] : 0;
        int tsum = h0 + h1 + h2;
        int x = tsum;
#pragma unroll
        for (int d = 1; d < 64; d <<= 1) {
            int t = __shfl_up(x, d);
            if (lane >= d) x += t;
        }
        if (lane == 63) wsum[wid] = x;
        __syncthreads();
        if (tid == 0) {
            int run = 0;
#pragma unroll
            for (int w = 0; w < 4; ++w) { int t = wsum[w]; wsum[w] = run; run += t; }
        }
        __syncthreads();
        int base = wsum[wid] + (x - tsum);
        if (b0 + 0 < nb) loff[b0 + 0] = base;
        if (b0 + 1 < nb) loff[b0 + 1] = base + h0;
        if (b0 + 2 < nb) loff[b0 + 2] = base + h0 + h1;
    }
    __syncthreads();
    for (int b = tid; b < nb; b += 256) {
        cur[b] = loff[b];
        int c = hist[b];
        gbase[b] = c > 0 ? atomicAdd(&gcur[b], c) : 0;
    }
    __syncthreads();
    for (int i = beg + tid; i < end; i += 256) {
        int p = prim[i], s = sec[i];
        int b = p >> NPB_LOG2;
        int l = atomicAdd(&cur[b], 1);
        sbuf[l] = ((uint32_t)p << 16) | (uint32_t)s;
    }
    __syncthreads();
    for (int b = wid; b < nb; b += 4) {
        int lo = loff[b], cnt = hist[b], gb = gbase[b];
        for (int k = lane; k < cnt; k += 64)
            out[gb + k] = sbuf[lo + k];
    }
}

// Counting sort of one bucket's segment by dst, in place (LDS-staged), AND
// write isd[node] = rsqrt(degree) from the self-computed histogram (every
// edge of node d is in bucket d>>6, so hist = full degree).
__global__ __launch_bounds__(256) void bsort3_kernel(
        uint32_t* __restrict__ buf, const int* __restrict__ boff,
        float* __restrict__ isd, int n_rows) {
    __shared__ uint32_t stage[SORT_CAP];
    __shared__ int hist[NPB];
    __shared__ int cur[NPB];
    const int tid = threadIdx.x;
    const int jbeg = boff[blockIdx.x];
    const int cnt = boff[blockIdx.x + 1] - jbeg;
    const bool fits = (cnt <= SORT_CAP);   // sort is perf-only; isd always written
    if (tid < NPB) hist[tid] = 0;
    __syncthreads();
    for (int k = tid; k < cnt; k += 256) {
        uint32_t p = buf[jbeg + k];
        if (fits) stage[k] = p;
        atomicAdd(&hist[(p >> 16) & (NPB - 1)], 1);
    }
    __syncthreads();   // drains global reads before in-place overwrite
    if (tid < NPB) {   // wave 0: 64-wide exclusive scan via shfl + isd write
        int h = hist[tid];
        int x = h;
#pragma unroll
        for (int d = 1; d < 64; d <<= 1) {
            int t = __shfl_up(x, d);
            if (tid >= d) x += t;
        }
        cur[tid] = x - h;
        int node = (blockIdx.x << NPB_LOG2) + tid;
        if (node < n_rows) isd[node] = h > 0 ? rsqrtf((float)h) : 0.f;
    }
    __syncthreads();
    if (fits) {
        for (int k = tid; k < cnt; k += 256) {
            uint32_t p = stage[k];
            int slot = atomicAdd(&cur[(p >> 16) & (NPB - 1)], 1);
            buf[jbeg + slot] = p;
        }
    }
}

// Wave per CSCAN_CH consecutive dst-sorted edges; register accumulate,
// flush on dst change via native f32 atomic. Software-pipelined: rows for
// group g+1 issued BEFORE PROC(g); packed runs 2 groups ahead. Uniform-group
// (endpoints same dst, sorted => all same) takes a branch-free add-tree.
__global__ __launch_bounds__(256) void cscan_kernel(
        const ushort* __restrict__ xb, const uint32_t* __restrict__ packed, int E,
        const float* __restrict__ isd, float* __restrict__ out) {
    const int lane = threadIdx.x & 63;
    const int wave = (blockIdx.x << 2) + (threadIdx.x >> 6);
    const int base = wave * CSCAN_CH;
    if (base >= E) return;
    const int n = min(CSCAN_CH, E - base);
    const uint32_t* pp = packed + base;
    float ax = 0.f, ay = 0.f;
    int cur = (int)(pp[0] >> 16);

#define ROW(pv) (*reinterpret_cast<const uint32_t*>( \
        xb + (((size_t)((pv) & 0xffffu)) << 7) + (lane << 1)))
#define UPX(rv) __uint_as_float((rv) << 16)
#define UPY(rv) __uint_as_float((rv) & 0xffff0000u)
#define FLUSH() do { float w_ = isd[cur];                                  \
        unsafeAtomicAdd(out + ((size_t)cur << 7) + lane, ax * w_);         \
        unsafeAtomicAdd(out + ((size_t)cur << 7) + 64 + lane, ay * w_);    \
        ax = 0.f; ay = 0.f; } while (0)
#define PROC(pv, rv) do { int d_ = (int)((pv) >> 16);                      \
        if (d_ != cur) { FLUSH(); cur = d_; }                              \
        ax += UPX(rv); ay += UPY(rv); } while (0)
#define GRP8(Aa, Ab, r0, r1, r2, r3, r4, r5, r6, r7) do {                  \
    if ((((Aa.x ^ Ab.w) >> 16) == 0) && ((int)(Aa.x >> 16) == cur)) {      \
        float sx = ((UPX(r0) + UPX(r1)) + (UPX(r2) + UPX(r3)))             \
                 + ((UPX(r4) + UPX(r5)) + (UPX(r6) + UPX(r7)));            \
        float sy = ((UPY(r0) + UPY(r1)) + (UPY(r2) + UPY(r3)))             \
                 + ((UPY(r4) + UPY(r5)) + (UPY(r6) + UPY(r7)));            \
        ax += sx; ay += sy;                                                \
    } else {                                                               \
        PROC(Aa.x, r0); PROC(Aa.y, r1); PROC(Aa.z, r2); PROC(Aa.w, r3);    \
        PROC(Ab.x, r4); PROC(Ab.y, r5); PROC(Ab.z, r6); PROC(Ab.w, r7);    \
    } } while (0)

    int k = 0;
    if (n >= 24) {
        uint4 P0a = *(const uint4*)(pp + 0),  P0b = *(const uint4*)(pp + 4);
        uint4 P1a = *(const uint4*)(pp + 8),  P1b = *(const uint4*)(pp + 12);
        uint32_t a0 = ROW(P0a.x), a1 = ROW(P0a.y), a2 = ROW(P0a.z), a3 = ROW(P0a.w),
                 a4 = ROW(P0b.x), a5 = ROW(P0b.y), a6 = ROW(P0b.z), a7 = ROW(P0b.w);
        uint4 P2a = *(const uint4*)(pp + 16), P2b = *(const uint4*)(pp + 20);
        uint32_t b0 = ROW(P1a.x), b1 = ROW(P1a.y), b2 = ROW(P1a.z), b3 = ROW(P1a.w),
                 b4 = ROW(P1b.x), b5 = ROW(P1b.y), b6 = ROW(P1b.z), b7 = ROW(P1b.w);
        for (k = 24; k + 8 <= n; k += 8) {
            uint4 P3a = *(const uint4*)(pp + k), P3b = *(const uint4*)(pp + k + 4);
            uint32_t c0 = ROW(P2a.x), c1 = ROW(P2a.y), c2 = ROW(P2a.z), c3 = ROW(P2a.w),
                     c4 = ROW(P2b.x), c5 = ROW(P2b.y), c6 = ROW(P2b.z), c7 = ROW(P2b.w);
            GRP8(P0a, P0b, a0, a1, a2, a3, a4, a5, a6, a7);
            P0a = P1a; P0b = P1b; P1a = P2a; P1b = P2b; P2a = P3a; P2b = P3b;
            a0 = b0; a1 = b1; a2 = b2; a3 = b3; a4 = b4; a5 = b5; a6 = b6; a7 = b7;
            b0 = c0; b1 = c1; b2 = c2; b3 = c3; b4 = c4; b5 = c5; b6 = c6; b7 = c7;
        }
        uint32_t c0 = ROW(P2a.x), c1 = ROW(P2a.y), c2 = ROW(P2a.z), c3 = ROW(P2a.w),
                 c4 = ROW(P2b.x), c5 = ROW(P2b.y), c6 = ROW(P2b.z), c7 = ROW(P2b.w);
        GRP8(P0a, P0b, a0, a1, a2, a3, a4, a5, a6, a7);
        GRP8(P1a, P1b, b0, b1, b2, b3, b4, b5, b6, b7);
        GRP8(P2a, P2b, c0, c1, c2, c3, c4, c5, c6, c7);
    }
    for (; k < n; ++k) {
        uint32_t p = pp[k];
        uint32_t r = ROW(p);
        PROC(p, r);
    }
    FLUSH();
#undef GRP8
#undef PROC
#undef FLUSH
#undef UPY
#undef UPX
#undef ROW
}

// ---- fallback-path kernels (rounds 2/4 proven) ----------------------------

__global__ __launch_bounds__(1024) void scan_kernel(const int* __restrict__ in,
                                                    int* __restrict__ out, int n) {
    __shared__ int ws[17];
    const int tid  = threadIdx.x;
    const int lane = tid & 63;
    const int wid  = tid >> 6;
    int carry = 0;  // meaningful on tid 0 only
    for (int base = 0; base < n; base += 4096) {
        int idx = base + tid * 4;
        int v0 = (idx + 0 < n) ? in[idx + 0] : 0;
        int v1 = (idx + 1 < n) ? in[idx + 1] : 0;
        int v2 = (idx + 2 < n) ? in[idx + 2] : 0;
        int v3 = (idx + 3 < n) ? in[idx + 3] : 0;
        int tsum = v0 + v1 + v2 + v3;
        int x = tsum;
#pragma unroll
        for (int d = 1; d < 64; d <<= 1) {
            int t = __shfl_up(x, d);
            if (lane >= d) x += t;
        }
        if (lane == 63) ws[wid] = x;
        __syncthreads();
        if (tid == 0) {
            int run = carry;
#pragma unroll
            for (int w = 0; w < 16; ++w) { int t = ws[w]; ws[w] = run; run += t; }
            carry = run;
        }
        __syncthreads();
        int excl = ws[wid] + (x - tsum);
        if (idx + 0 < n) out[idx + 0] = excl; excl += v0;
        if (idx + 1 < n) out[idx + 1] = excl; excl += v1;
        if (idx + 2 < n) out[idx + 2] = excl; excl += v2;
        if (idx + 3 < n) out[idx + 3] = excl;
        __syncthreads();
    }
    if (tid == 0) out[n] = carry;
}

__global__ void deg_kernel(const int* __restrict__ u, const int* __restrict__ s,
                           int E, int* __restrict__ udeg, int* __restrict__ sdeg) {
    int i = blockIdx.x * blockDim.x + threadIdx.x;
    int i4 = i * 4;
    if (i4 + 3 < E) {
        int4 a = *reinterpret_cast<const int4*>(u + i4);
        int4 b = *reinterpret_cast<const int4*>(s + i4);
        atomicAdd(&udeg[a.x], 1); atomicAdd(&udeg[a.y], 1);
        atomicAdd(&udeg[a.z], 1); atomicAdd(&udeg[a.w], 1);
        atomicAdd(&sdeg[b.x], 1); atomicAdd(&sdeg[b.y], 1);
        atomicAdd(&sdeg[b.z], 1); atomicAdd(&sdeg[b.w], 1);
    } else {
        for (int k = i4; k < E; ++k) {
            atomicAdd(&udeg[u[k]], 1);
            atomicAdd(&sdeg[s[k]], 1);
        }
    }
}

__global__ void init_isd_kernel(const int* __restrict__ udeg, const int* __restrict__ sdeg,
                                float* __restrict__ isd_u, float* __restrict__ isd_s,
                                int n_user, int m_spot) {
    int i = blockIdx.x * blockDim.x + threadIdx.x;
    if (i < n_user) { int d = udeg[i]; isd_u[i] = d > 0 ? rsqrtf((float)d) : 0.f; }
    if (i < m_spot) { int d = sdeg[i]; isd_s[i] = d > 0 ? rsqrtf((float)d) : 0.f; }
}

__global__ void breduce_kernel(const int* __restrict__ udeg, const int* __restrict__ sdeg,
                               int N, int M, int nbu, int nbs,
                               int* __restrict__ bdu, int* __restrict__ bds) {
    const int w = (blockIdx.x * blockDim.x + threadIdx.x) >> 6;
    const int lane = threadIdx.x & 63;
    if (w >= nbu + nbs) return;
    int v;
    if (w < nbu) {
        int i = (w << NPB_LOG2) + lane;
        v = (i < N) ? udeg[i] : 0;
    } else {
        int i = ((w - nbu) << NPB_LOG2) + lane;
        v = (i < M) ? sdeg[i] : 0;
    }
#pragma unroll
    for (int d = 32; d >= 1; d >>= 1) v += __shfl_down(v, d);
    if (lane == 0) {
        if (w < nbu) bdu[w] = v; else bds[w - nbu] = v;
    }
}

__global__ void gcur3_init_kernel(const int* __restrict__ buoff, const int* __restrict__ bsoff,
                                  int* __restrict__ gcu, int* __restrict__ gcs,
                                  int nbu, int nbs) {
    int i = blockIdx.x * blockDim.x + threadIdx.x;
    if (i < nbu) gcu[i] = buoff[i];
    if (i < nbs) gcs[i] = bsoff[i];
}

__global__ void gcur_init_kernel(const int* __restrict__ uoff, const int* __restrict__ soff,
                                 int* __restrict__ gcur_u, int* __restrict__ gcur_s,
                                 int nbu, int nbs) {
    int i = blockIdx.x * blockDim.x + threadIdx.x;
    if (i < nbu) gcur_u[i] = uoff[i << NPB_LOG2];
    if (i < nbs) gcur_s[i] = soff[i << NPB_LOG2];
}

__global__ __launch_bounds__(256) void bsort_kernel(
        const uint32_t* __restrict__ packed, const int* __restrict__ noff,
        int nodes, int* __restrict__ csr) {
    __shared__ int cur[NPB];
    const int tid = threadIdx.x;
    const int ubase = blockIdx.x << NPB_LOG2;
    const int nin = min(NPB, nodes - ubase);
    if (tid < nin) cur[tid] = noff[ubase + tid];
    __syncthreads();
    const int jbeg = noff[ubase];
    const int jend = noff[ubase + nin];
    for (int j = jbeg + tid; j < jend; j += 256) {
        uint32_t p = packed[j];
        int local = (int)(p >> 16) - ubase;
        int slot = atomicAdd(&cur[local], 1);
        csr[slot] = (int)(p & 0xffffu);
    }
}

__global__ __launch_bounds__(256) void gather_kernel(const float* __restrict__ x_src,
                                                     const int* __restrict__ nbr,
                                                     const int* __restrict__ off,
                                                     const float* __restrict__ isd_dst,
                                                     const float* __restrict__ isd_src,
                                                     float* __restrict__ out, int n_rows) {
    const int lane = threadIdx.x & 63;
    const int row  = blockIdx.x * 4 + (threadIdx.x >> 6);
    if (row >= n_rows) return;
    const int jbeg = off[row];
    const int jend = off[row + 1];
    const float wd = isd_dst[row];
    float ax = 0.f, ay = 0.f;
    if (jbeg < jend) {
        int sidx = nbr[jbeg];
        for (int j = jbeg; j < jend; ++j) {
            int snext = (j + 1 < jend) ? nbr[j + 1] : 0;
            float w = wd * isd_src[sidx];
            const float2 v = *reinterpret_cast<const float2*>(x_src + (size_t)sidx * 128 + lane * 2);
            ax = fmaf(v.x, w, ax);
            ay = fmaf(v.y, w, ay);
            sidx = snext;
        }
    }
    float2 r; r.x = ax; r.y = ay;
    *reinterpret_cast<float2*>(out + (size_t)row * 128 + lane * 2) = r;
}

__global__ __launch_bounds__(256) void scatter_kernel(const float* __restrict__ spot_x,
                                                      const float* __restrict__ user_x,
                                                      const int* __restrict__ u,
                                                      const int* __restrict__ s, int E,
                                                      const float* __restrict__ isd_u,
                                                      const float* __restrict__ isd_s,
                                                      float* __restrict__ spot_out,
                                                      float* __restrict__ user_out) {
    const int lane = threadIdx.x & 63;
    const int e = blockIdx.x * 4 + (threadIdx.x >> 6);
    if (e >= E) return;
    const int uu = u[e], ss = s[e];
    const float w = isd_u[uu] * isd_s[ss];
    const float2 sv = *reinterpret_cast<const float2*>(spot_x + (size_t)ss * 128 + lane * 2);
    const float2 uv = *reinterpret_cast<const float2*>(user_x + (size_t)uu * 128 + lane * 2);
    atomicAdd(&user_out[(size_t)uu * 128 + lane * 2 + 0], sv.x * w);
    atomicAdd(&user_out[(size_t)uu * 128 + lane * 2 + 1], sv.y * w);
    atomicAdd(&spot_out[(size_t)ss * 128 + lane * 2 + 0], uv.x * w);
    atomicAdd(&spot_out[(size_t)ss * 128 + lane * 2 + 1], uv.y * w);
}

static inline char* align256(char* p) {
    return (char*)(((uintptr_t)p + 255u) & ~(uintptr_t)255u);
}

extern "C" void kernel_launch(void* const* d_in, const int* in_sizes, int n_in,
                              void* d_out, int out_size, void* d_ws, size_t ws_size,
                              hipStream_t stream) {
    const float* spot_x = (const float*)d_in[0];
    const float* user_x = (const float*)d_in[1];
    const int*   edges  = (const int*)d_in[2];
    const int M = in_sizes[0] / 128;   // spots
    const int N = in_sizes[1] / 128;   // users
    const int E = in_sizes[2] / 2;
    const int* u = edges;        // user_spot[0]
    const int* s = edges + E;    // user_spot[1]
    float* spot_out = (float*)d_out;
    float* user_out = (float*)d_out + (size_t)M * 128;

    const int nbu = (N + NPB - 1) / NPB;
    const int nbs = (M + NPB - 1) / NPB;
    const int nm = (N > M) ? N : M;
    const int gpart = (E + PART_CHUNK - 1) / PART_CHUNK;
    const int gscan = ((E + CSCAN_CH - 1) / CSCAN_CH + 3) / 4;

    // ---------------- fast-path layout (deg-free, 2 edge buffers) ----------
    {
        char* ws = (char*)d_ws;
        float*    isd_u = (float*)ws; ws = align256(ws + sizeof(float) * (size_t)N);
        float*    isd_s = (float*)ws; ws = align256(ws + sizeof(float) * (size_t)M);
        int*      bd    = (int*)ws;   ws = align256(ws + sizeof(int) * (size_t)(nbu + nbs));
        int*      buoff = (int*)ws;   ws = align256(ws + sizeof(int) * (size_t)(nbu + 1));
        int*      bsoff = (int*)ws;   ws = align256(ws + sizeof(int) * (size_t)(nbs + 1));
        int*      gcu   = (int*)ws;   ws = align256(ws + sizeof(int) * (size_t)nbu);
        int*      gcs   = (int*)ws;   ws = align256(ws + sizeof(int) * (size_t)nbs);
        uint32_t* bufU  = (uint32_t*)ws; ws = align256(ws + sizeof(uint32_t) * (size_t)E);
        uint32_t* bufS  = (uint32_t*)ws; ws = align256(ws + sizeof(uint32_t) * (size_t)E);
        ushort*   xb    = (ushort*)ws;   // union: spot table, then user table
        size_t fast_needed = (size_t)(ws - (char*)d_ws) + sizeof(ushort) * ((size_t)nm * 128);

        if (fast_needed <= ws_size && nbu <= MAXB && nbs <= MAXB) {
            hipMemsetAsync(bd, 0, sizeof(int) * (size_t)(nbu + nbs), stream);
            hipMemsetAsync(d_out, 0, sizeof(float) * (size_t)out_size, stream);
            bhist_kernel<<<(E + BH_CHUNK - 1) / BH_CHUNK, 256, 0, stream>>>(
                u, s, E, nbu, nbs, bd);
            scan2_kernel<<<2, 1024, 0, stream>>>(bd, nbu, nbs, buoff, bsoff, gcu, gcs);
            part_kernel<<<gpart, 256, 0, stream>>>(u, s, E, nbu, gcu, bufU);
            part_kernel<<<gpart, 256, 0, stream>>>(s, u, E, nbs, gcs, bufS);
            bsort3_kernel<<<nbu, 256, 0, stream>>>(bufU, buoff, isd_u, N);
            bsort3_kernel<<<nbs, 256, 0, stream>>>(bufS, bsoff, isd_s, M);
            // user direction: spot table scaled by isd_s, flush by isd_u
            convert_kernel<<<((M << 6) + 255) / 256, 256, 0, stream>>>(spot_x, isd_s, xb, M);
            cscan_kernel<<<gscan, 256, 0, stream>>>(xb, bufU, E, isd_u, user_out);
            // spot direction: user table (same union slot) scaled by isd_u
            convert_kernel<<<((N << 6) + 255) / 256, 256, 0, stream>>>(user_x, isd_u, xb, N);
            cscan_kernel<<<gscan, 256, 0, stream>>>(xb, bufS, E, isd_s, spot_out);
            return;
        }
    }

    // ---------------- fallback layouts (round-4 proven) --------------------
    char* ws = (char*)d_ws;
    int*      udeg  = (int*)ws;  ws = align256(ws + sizeof(int) * (size_t)(N + M));
    int*      sdeg  = udeg + N;
    float*    isd_u = (float*)ws; ws = align256(ws + sizeof(float) * (size_t)N);
    float*    isd_s = (float*)ws; ws = align256(ws + sizeof(float) * (size_t)M);
    size_t fallback_needed = (size_t)(ws - (char*)d_ws);
    int*      uoff  = (int*)ws;  ws = align256(ws + sizeof(int) * (size_t)(N + 1));
    int*      soff  = (int*)ws;  ws = align256(ws + sizeof(int) * (size_t)(M + 1));
    int*      bdu   = (int*)ws;  ws = align256(ws + sizeof(int) * (size_t)nbu);
    int*      bds   = (int*)ws;  ws = align256(ws + sizeof(int) * (size_t)nbs);
    int*      buoff = (int*)ws;  ws = align256(ws + sizeof(int) * (size_t)(nbu + 1));
    int*      bsoff = (int*)ws;  ws = align256(ws + sizeof(int) * (size_t)(nbs + 1));
    int*      gcu   = (int*)ws;  ws = align256(ws + sizeof(int) * (size_t)nbu);
    int*      gcs   = (int*)ws;  ws = align256(ws + sizeof(int) * (size_t)nbs);
    uint32_t* bufA  = (uint32_t*)ws; ws = align256(ws + sizeof(uint32_t) * (size_t)E);
    char* mark = ws;
    ushort*   xbs   = (ushort*)mark;
    ushort*   xbu   = (ushort*)align256(mark + sizeof(ushort) * ((size_t)M * 128));
    size_t new_needed = (size_t)((char*)xbu - (char*)d_ws) + sizeof(ushort) * ((size_t)N * 128);
    int*      bufB  = (int*)mark;
    size_t old_needed = (size_t)(mark - (char*)d_ws) + sizeof(int) * (size_t)E;

    hipMemsetAsync(udeg, 0, sizeof(int) * (size_t)(N + M), stream);
    deg_kernel<<<(E / 4 + 255) / 256, 256, 0, stream>>>(u, s, E, udeg, sdeg);
    init_isd_kernel<<<(nm + 255) / 256, 256, 0, stream>>>(udeg, sdeg, isd_u, isd_s, N, M);

    if (new_needed <= ws_size && nbu <= MAXB && nbs <= MAXB) {
        convert_kernel<<<((M << 6) + 255) / 256, 256, 0, stream>>>(spot_x, isd_s, xbs, M);
        convert_kernel<<<((N << 6) + 255) / 256, 256, 0, stream>>>(user_x, isd_u, xbu, N);
        breduce_kernel<<<((nbu + nbs) * 64 + 255) / 256, 256, 0, stream>>>(
            udeg, sdeg, N, M, nbu, nbs, bdu, bds);
        scan_kernel<<<1, 1024, 0, stream>>>(bdu, buoff, nbu);
        scan_kernel<<<1, 1024, 0, stream>>>(bds, bsoff, nbs);
        gcur3_init_kernel<<<(nbs + nbu + 255) / 256, 256, 0, stream>>>(
            buoff, bsoff, gcu, gcs, nbu, nbs);
        hipMemsetAsync(d_out, 0, sizeof(float) * (size_t)out_size, stream);
        part_kernel<<<gpart, 256, 0, stream>>>(u, s, E, nbu, gcu, bufA);
        bsort3_kernel<<<nbu, 256, 0, stream>>>(bufA, buoff, isd_u, N);
        cscan_kernel<<<gscan, 256, 0, stream>>>(xbs, bufA, E, isd_u, user_out);
        part_kernel<<<gpart, 256, 0, stream>>>(s, u, E, nbs, gcs, bufA);
        bsort3_kernel<<<nbs, 256, 0, stream>>>(bufA, bsoff, isd_s, M);
        cscan_kernel<<<gscan, 256, 0, stream>>>(xbu, bufA, E, isd_s, spot_out);
    } else if (old_needed <= ws_size && nbu <= MAXB && nbs <= MAXB) {
        scan_kernel<<<1, 1024, 0, stream>>>(udeg, uoff, N);
        scan_kernel<<<1, 1024, 0, stream>>>(sdeg, soff, M);
        gcur_init_kernel<<<(nbs + nbu + 255) / 256, 256, 0, stream>>>(uoff, soff, gcu, gcs, nbu, nbs);
        part_kernel<<<gpart, 256, 0, stream>>>(u, s, E, nbu, gcu, bufA);
        bsort_kernel<<<nbu, 256, 0, stream>>>(bufA, uoff, N, bufB);
        gather_kernel<<<(N + 3) / 4, 256, 0, stream>>>(spot_x, bufB, uoff,
                                                       isd_u, isd_s, user_out, N);
        part_kernel<<<gpart, 256, 0, stream>>>(s, u, E, nbs, gcs, bufA);
        bsort_kernel<<<nbs, 256, 0, stream>>>(bufA, soff, M, bufB);
        gather_kernel<<<(M + 3) / 4, 256, 0, stream>>>(user_x, bufB, soff,
                                                       isd_s, isd_u, spot_out, M);
    } else if (fallback_needed <= ws_size) {
        hipMemsetAsync(d_out, 0, sizeof(float) * (size_t)out_size, stream);
        scatter_kernel<<<((size_t)E + 3) / 4, 256, 0, stream>>>(spot_x, user_x, u, s, E,
                                                                isd_u, isd_s, spot_out, user_out);
    }
}

// Round 7
// 270.386 us; speedup vs baseline: 12.6879x; 1.0735x over previous
//
#include <hip/hip_runtime.h>
#include <stdint.h>

// ---------------------------------------------------------------------------
// UserSpotConv: bipartite GCN aggregation.
//   user_out[u] = isd_u[u] * sum_{e: u_e=u} spot_x[s_e] * isd_s[s_e]
//   spot_out[s] = isd_s[s] * sum_{e: s_e=s} user_x[u_e] * isd_u[u_e]
// Round 7: part_kernel was grid-starved (245 blocks on 256 CUs, 9% occ,
// 57 us). PART_CHUNK 8192->2048 (977 blocks, 20.5 KB LDS, 7 blocks/CU) and
// element-parallel coalesced flush (runs are ~5 edges now; wave-per-bucket
// flush would idle 59/64 lanes). cscan left alone: two different schedules
// both hit 60 us @ FETCH 166 MB -> bound by random-row L2-miss path.
// ---------------------------------------------------------------------------

#define NPB_LOG2 6
#define NPB 64             // destination nodes per bucket
#define MAXB 768           // max buckets per direction
#define PART_CHUNK 2048    // edges per block in part_kernel
#define BH_CHUNK 16384     // edges per block in bhist_kernel
#define SORT_CAP 8192      // max edges per bucket for bsort3 staging
#define CSCAN_CH 256       // edges per wave in cscan

__device__ __forceinline__ ushort f2bf(float f) {
    uint32_t u = __float_as_uint(f);
    return (ushort)((u + 0x7fffu + ((u >> 16) & 1u)) >> 16);  // RNE
}

// Bucket-level histogram for BOTH directions in one pass. LDS-staged so the
// global atomic count is ~nb per block (not per edge).
__global__ __launch_bounds__(256) void bhist_kernel(
        const int* __restrict__ u, const int* __restrict__ s, int E,
        int nbu, int nbs, int* __restrict__ bd) {
    __shared__ int hist[2 * MAXB];
    const int tid = threadIdx.x;
    const int nb = nbu + nbs;
    const int beg = blockIdx.x * BH_CHUNK;
    const int end = min(beg + BH_CHUNK, E);
    for (int b = tid; b < nb; b += 256) hist[b] = 0;
    __syncthreads();
    for (int i = beg + tid; i < end; i += 256) {
        atomicAdd(&hist[u[i] >> NPB_LOG2], 1);
        atomicAdd(&hist[nbu + (s[i] >> NPB_LOG2)], 1);
    }
    __syncthreads();
    for (int b = tid; b < nb; b += 256) {
        int h = hist[b];
        if (h) atomicAdd(&bd[b], h);
    }
}

// Fused dual exclusive scan (block 0: u-buckets, block 1: s-buckets) that
// also initializes the part_kernel global cursors. n <= 1024 (MAXB=768).
__global__ __launch_bounds__(1024) void scan2_kernel(
        const int* __restrict__ bd, int nbu, int nbs,
        int* __restrict__ buoff, int* __restrict__ bsoff,
        int* __restrict__ gcu, int* __restrict__ gcs) {
    __shared__ int wsums[16];
    __shared__ int total;
    const int tid = threadIdx.x, lane = tid & 63, wid = tid >> 6;
    const int n   = blockIdx.x ? nbs : nbu;
    const int* in = blockIdx.x ? (bd + nbu) : bd;
    int* out = blockIdx.x ? bsoff : buoff;
    int* gc  = blockIdx.x ? gcs   : gcu;
    int v = (tid < n) ? in[tid] : 0;
    int x = v;
#pragma unroll
    for (int d = 1; d < 64; d <<= 1) {
        int t = __shfl_up(x, d);
        if (lane >= d) x += t;
    }
    if (lane == 63) wsums[wid] = x;
    __syncthreads();
    if (tid == 0) {
        int run = 0;
#pragma unroll
        for (int w = 0; w < 16; ++w) { int t = wsums[w]; wsums[w] = run; run += t; }
        total = run;
    }
    __syncthreads();
    int excl = wsums[wid] + (x - v);
    if (tid < n) { out[tid] = excl; gc[tid] = excl; }
    if (tid == 0) out[n] = total;
}

// xb row layout is PERMUTED: slot 2c holds col c, slot 2c+1 holds col c+64,
// so a lane's uint32 load at byte row*256+4*l yields cols (l, l+64).
__global__ void convert_kernel(const float* __restrict__ x, const float* __restrict__ isd,
                               ushort* __restrict__ xb, int n_rows) {
    int idx = blockIdx.x * blockDim.x + threadIdx.x;
    if (idx >= (n_rows << 6)) return;
    int row = idx >> 6, c = idx & 63;
    float w = isd[row];
    const float* xr = x + ((size_t)row << 7);
    ushort2 o;
    o.x = f2bf(xr[c] * w);
    o.y = f2bf(xr[c + 64] * w);
    *reinterpret_cast<ushort2*>(xb + ((size_t)row << 7) + 2 * c) = o;
}

// Partition edges into NPB-node buckets of the primary (destination) index.
// LDS-staged so global writes are contiguous per-bucket runs. Flush is
// element-parallel: sbuf is bucket-ordered so consecutive k -> consecutive
// global addresses (coalesced even for ~5-edge runs).
__global__ __launch_bounds__(256) void part_kernel(
        const int* __restrict__ prim, const int* __restrict__ sec, int E,
        int nb, int* __restrict__ gcur, uint32_t* __restrict__ out) {
    __shared__ int hist[MAXB];
    __shared__ int loff[MAXB];
    __shared__ int gbase[MAXB];
    __shared__ int cur[MAXB];
    __shared__ int wsum[4];
    __shared__ uint32_t sbuf[PART_CHUNK];
    const int tid = threadIdx.x;
    const int lane = tid & 63;
    const int wid = tid >> 6;
    const int beg = blockIdx.x * PART_CHUNK;
    const int end = min(beg + PART_CHUNK, E);
    const int cnt_total = end - beg;
    for (int b = tid; b < nb; b += 256) hist[b] = 0;
    __syncthreads();
    for (int i = beg + tid; i < end; i += 256)
        atomicAdd(&hist[prim[i] >> NPB_LOG2], 1);
    __syncthreads();
    // parallel exclusive scan of hist[0..nb) into loff (3 buckets per thread)
    {
        int b0 = tid * 3;
        int h0 = (b0 + 0 < nb) ? hist[b0 + 0] : 0;
        int h1 = (b0 + 1 < nb) ? hist[b0 + 1] : 0;
        int h2 = (b0 + 2 < nb) ? hist[b0 + 2] : 0;
        int tsum = h0 + h1 + h2;
        int x = tsum;
#pragma unroll
        for (int d = 1; d < 64; d <<= 1) {
            int t = __shfl_up(x, d);
            if (lane >= d) x += t;
        }
        if (lane == 63) wsum[wid] = x;
        __syncthreads();
        if (tid == 0) {
            int run = 0;
#pragma unroll
            for (int w = 0; w < 4; ++w) { int t = wsum[w]; wsum[w] = run; run += t; }
        }
        __syncthreads();
        int base = wsum[wid] + (x - tsum);
        if (b0 + 0 < nb) loff[b0 + 0] = base;
        if (b0 + 1 < nb) loff[b0 + 1] = base + h0;
        if (b0 + 2 < nb) loff[b0 + 2] = base + h0 + h1;
    }
    __syncthreads();
    for (int b = tid; b < nb; b += 256) {
        cur[b] = loff[b];
        int c = hist[b];
        gbase[b] = c > 0 ? atomicAdd(&gcur[b], c) : 0;
    }
    __syncthreads();
    for (int i = beg + tid; i < end; i += 256) {
        int p = prim[i], s = sec[i];
        int b = p >> NPB_LOG2;
        int l = atomicAdd(&cur[b], 1);
        sbuf[l] = ((uint32_t)p << 16) | (uint32_t)s;
    }
    __syncthreads();
    for (int k = tid; k < cnt_total; k += 256) {
        uint32_t p = sbuf[k];
        int b = (int)(p >> (16 + NPB_LOG2));
        out[gbase[b] + (k - loff[b])] = p;
    }
}

// Counting sort of one bucket's segment by dst, in place (LDS-staged), AND
// write isd[node] = rsqrt(degree) from the self-computed histogram (every
// edge of node d is in bucket d>>6, so hist = full degree).
__global__ __launch_bounds__(256) void bsort3_kernel(
        uint32_t* __restrict__ buf, const int* __restrict__ boff,
        float* __restrict__ isd, int n_rows) {
    __shared__ uint32_t stage[SORT_CAP];
    __shared__ int hist[NPB];
    __shared__ int cur[NPB];
    const int tid = threadIdx.x;
    const int jbeg = boff[blockIdx.x];
    const int cnt = boff[blockIdx.x + 1] - jbeg;
    const bool fits = (cnt <= SORT_CAP);   // sort is perf-only; isd always written
    if (tid < NPB) hist[tid] = 0;
    __syncthreads();
    for (int k = tid; k < cnt; k += 256) {
        uint32_t p = buf[jbeg + k];
        if (fits) stage[k] = p;
        atomicAdd(&hist[(p >> 16) & (NPB - 1)], 1);
    }
    __syncthreads();   // drains global reads before in-place overwrite
    if (tid < NPB) {   // wave 0: 64-wide exclusive scan via shfl + isd write
        int h = hist[tid];
        int x = h;
#pragma unroll
        for (int d = 1; d < 64; d <<= 1) {
            int t = __shfl_up(x, d);
            if (tid >= d) x += t;
        }
        cur[tid] = x - h;
        int node = (blockIdx.x << NPB_LOG2) + tid;
        if (node < n_rows) isd[node] = h > 0 ? rsqrtf((float)h) : 0.f;
    }
    __syncthreads();
    if (fits) {
        for (int k = tid; k < cnt; k += 256) {
            uint32_t p = stage[k];
            int slot = atomicAdd(&cur[(p >> 16) & (NPB - 1)], 1);
            buf[jbeg + slot] = p;
        }
    }
}

// Wave per CSCAN_CH consecutive dst-sorted edges; register accumulate,
// flush on dst change via native f32 atomic. Software-pipelined: rows for
// group g+1 issued BEFORE PROC(g); packed runs 2 groups ahead. Uniform-group
// (endpoints same dst, sorted => all same) takes a branch-free add-tree.
__global__ __launch_bounds__(256) void cscan_kernel(
        const ushort* __restrict__ xb, const uint32_t* __restrict__ packed, int E,
        const float* __restrict__ isd, float* __restrict__ out) {
    const int lane = threadIdx.x & 63;
    const int wave = (blockIdx.x << 2) + (threadIdx.x >> 6);
    const int base = wave * CSCAN_CH;
    if (base >= E) return;
    const int n = min(CSCAN_CH, E - base);
    const uint32_t* pp = packed + base;
    float ax = 0.f, ay = 0.f;
    int cur = (int)(pp[0] >> 16);

#define ROW(pv) (*reinterpret_cast<const uint32_t*>( \
        xb + (((size_t)((pv) & 0xffffu)) << 7) + (lane << 1)))
#define UPX(rv) __uint_as_float((rv) << 16)
#define UPY(rv) __uint_as_float((rv) & 0xffff0000u)
#define FLUSH() do { float w_ = isd[cur];                                  \
        unsafeAtomicAdd(out + ((size_t)cur << 7) + lane, ax * w_);         \
        unsafeAtomicAdd(out + ((size_t)cur << 7) + 64 + lane, ay * w_);    \
        ax = 0.f; ay = 0.f; } while (0)
#define PROC(pv, rv) do { int d_ = (int)((pv) >> 16);                      \
        if (d_ != cur) { FLUSH(); cur = d_; }                              \
        ax += UPX(rv); ay += UPY(rv); } while (0)
#define GRP8(Aa, Ab, r0, r1, r2, r3, r4, r5, r6, r7) do {                  \
    if ((((Aa.x ^ Ab.w) >> 16) == 0) && ((int)(Aa.x >> 16) == cur)) {      \
        float sx = ((UPX(r0) + UPX(r1)) + (UPX(r2) + UPX(r3)))             \
                 + ((UPX(r4) + UPX(r5)) + (UPX(r6) + UPX(r7)));            \
        float sy = ((UPY(r0) + UPY(r1)) + (UPY(r2) + UPY(r3)))             \
                 + ((UPY(r4) + UPY(r5)) + (UPY(r6) + UPY(r7)));            \
        ax += sx; ay += sy;                                                \
    } else {                                                               \
        PROC(Aa.x, r0); PROC(Aa.y, r1); PROC(Aa.z, r2); PROC(Aa.w, r3);    \
        PROC(Ab.x, r4); PROC(Ab.y, r5); PROC(Ab.z, r6); PROC(Ab.w, r7);    \
    } } while (0)

    int k = 0;
    if (n >= 24) {
        uint4 P0a = *(const uint4*)(pp + 0),  P0b = *(const uint4*)(pp + 4);
        uint4 P1a = *(const uint4*)(pp + 8),  P1b = *(const uint4*)(pp + 12);
        uint32_t a0 = ROW(P0a.x), a1 = ROW(P0a.y), a2 = ROW(P0a.z), a3 = ROW(P0a.w),
                 a4 = ROW(P0b.x), a5 = ROW(P0b.y), a6 = ROW(P0b.z), a7 = ROW(P0b.w);
        uint4 P2a = *(const uint4*)(pp + 16), P2b = *(const uint4*)(pp + 20);
        uint32_t b0 = ROW(P1a.x), b1 = ROW(P1a.y), b2 = ROW(P1a.z), b3 = ROW(P1a.w),
                 b4 = ROW(P1b.x), b5 = ROW(P1b.y), b6 = ROW(P1b.z), b7 = ROW(P1b.w);
        for (k = 24; k + 8 <= n; k += 8) {
            uint4 P3a = *(const uint4*)(pp + k), P3b = *(const uint4*)(pp + k + 4);
            uint32_t c0 = ROW(P2a.x), c1 = ROW(P2a.y), c2 = ROW(P2a.z), c3 = ROW(P2a.w),
                     c4 = ROW(P2b.x), c5 = ROW(P2b.y), c6 = ROW(P2b.z), c7 = ROW(P2b.w);
            GRP8(P0a, P0b, a0, a1, a2, a3, a4, a5, a6, a7);
            P0a = P1a; P0b = P1b; P1a = P2a; P1b = P2b; P2a = P3a; P2b = P3b;
            a0 = b0; a1 = b1; a2 = b2; a3 = b3; a4 = b4; a5 = b5; a6 = b6; a7 = b7;
            b0 = c0; b1 = c1; b2 = c2; b3 = c3; b4 = c4; b5 = c5; b6 = c6; b7 = c7;
        }
        uint32_t c0 = ROW(P2a.x), c1 = ROW(P2a.y), c2 = ROW(P2a.z), c3 = ROW(P2a.w),
                 c4 = ROW(P2b.x), c5 = ROW(P2b.y), c6 = ROW(P2b.z), c7 = ROW(P2b.w);
        GRP8(P0a, P0b, a0, a1, a2, a3, a4, a5, a6, a7);
        GRP8(P1a, P1b, b0, b1, b2, b3, b4, b5, b6, b7);
        GRP8(P2a, P2b, c0, c1, c2, c3, c4, c5, c6, c7);
    }
    for (; k < n; ++k) {
        uint32_t p = pp[k];
        uint32_t r = ROW(p);
        PROC(p, r);
    }
    FLUSH();
#undef GRP8
#undef PROC
#undef FLUSH
#undef UPY
#undef UPX
#undef ROW
}

// ---- fallback-path kernels (rounds 2/4 proven) ----------------------------

__global__ __launch_bounds__(1024) void scan_kernel(const int* __restrict__ in,
                                                    int* __restrict__ out, int n) {
    __shared__ int ws[17];
    const int tid  = threadIdx.x;
    const int lane = tid & 63;
    const int wid  = tid >> 6;
    int carry = 0;  // meaningful on tid 0 only
    for (int base = 0; base < n; base += 4096) {
        int idx = base + tid * 4;
        int v0 = (idx + 0 < n) ? in[idx + 0] : 0;
        int v1 = (idx + 1 < n) ? in[idx + 1] : 0;
        int v2 = (idx + 2 < n) ? in[idx + 2] : 0;
        int v3 = (idx + 3 < n) ? in[idx + 3] : 0;
        int tsum = v0 + v1 + v2 + v3;
        int x = tsum;
#pragma unroll
        for (int d = 1; d < 64; d <<= 1) {
            int t = __shfl_up(x, d);
            if (lane >= d) x += t;
        }
        if (lane == 63) ws[wid] = x;
        __syncthreads();
        if (tid == 0) {
            int run = carry;
#pragma unroll
            for (int w = 0; w < 16; ++w) { int t = ws[w]; ws[w] = run; run += t; }
            carry = run;
        }
        __syncthreads();
        int excl = ws[wid] + (x - tsum);
        if (idx + 0 < n) out[idx + 0] = excl; excl += v0;
        if (idx + 1 < n) out[idx + 1] = excl; excl += v1;
        if (idx + 2 < n) out[idx + 2] = excl; excl += v2;
        if (idx + 3 < n) out[idx + 3] = excl;
        __syncthreads();
    }
    if (tid == 0) out[n] = carry;
}

__global__ void deg_kernel(const int* __restrict__ u, const int* __restrict__ s,
                           int E, int* __restrict__ udeg, int* __restrict__ sdeg) {
    int i = blockIdx.x * blockDim.x + threadIdx.x;
    int i4 = i * 4;
    if (i4 + 3 < E) {
        int4 a = *reinterpret_cast<const int4*>(u + i4);
        int4 b = *reinterpret_cast<const int4*>(s + i4);
        atomicAdd(&udeg[a.x], 1); atomicAdd(&udeg[a.y], 1);
        atomicAdd(&udeg[a.z], 1); atomicAdd(&udeg[a.w], 1);
        atomicAdd(&sdeg[b.x], 1); atomicAdd(&sdeg[b.y], 1);
        atomicAdd(&sdeg[b.z], 1); atomicAdd(&sdeg[b.w], 1);
    } else {
        for (int k = i4; k < E; ++k) {
            atomicAdd(&udeg[u[k]], 1);
            atomicAdd(&sdeg[s[k]], 1);
        }
    }
}

__global__ void init_isd_kernel(const int* __restrict__ udeg, const int* __restrict__ sdeg,
                                float* __restrict__ isd_u, float* __restrict__ isd_s,
                                int n_user, int m_spot) {
    int i = blockIdx.x * blockDim.x + threadIdx.x;
    if (i < n_user) { int d = udeg[i]; isd_u[i] = d > 0 ? rsqrtf((float)d) : 0.f; }
    if (i < m_spot) { int d = sdeg[i]; isd_s[i] = d > 0 ? rsqrtf((float)d) : 0.f; }
}

__global__ void breduce_kernel(const int* __restrict__ udeg, const int* __restrict__ sdeg,
                               int N, int M, int nbu, int nbs,
                               int* __restrict__ bdu, int* __restrict__ bds) {
    const int w = (blockIdx.x * blockDim.x + threadIdx.x) >> 6;
    const int lane = threadIdx.x & 63;
    if (w >= nbu + nbs) return;
    int v;
    if (w < nbu) {
        int i = (w << NPB_LOG2) + lane;
        v = (i < N) ? udeg[i] : 0;
    } else {
        int i = ((w - nbu) << NPB_LOG2) + lane;
        v = (i < M) ? sdeg[i] : 0;
    }
#pragma unroll
    for (int d = 32; d >= 1; d >>= 1) v += __shfl_down(v, d);
    if (lane == 0) {
        if (w < nbu) bdu[w] = v; else bds[w - nbu] = v;
    }
}

__global__ void gcur3_init_kernel(const int* __restrict__ buoff, const int* __restrict__ bsoff,
                                  int* __restrict__ gcu, int* __restrict__ gcs,
                                  int nbu, int nbs) {
    int i = blockIdx.x * blockDim.x + threadIdx.x;
    if (i < nbu) gcu[i] = buoff[i];
    if (i < nbs) gcs[i] = bsoff[i];
}

__global__ void gcur_init_kernel(const int* __restrict__ uoff, const int* __restrict__ soff,
                                 int* __restrict__ gcur_u, int* __restrict__ gcur_s,
                                 int nbu, int nbs) {
    int i = blockIdx.x * blockDim.x + threadIdx.x;
    if (i < nbu) gcur_u[i] = uoff[i << NPB_LOG2];
    if (i < nbs) gcur_s[i] = soff[i << NPB_LOG2];
}

__global__ __launch_bounds__(256) void bsort_kernel(
        const uint32_t* __restrict__ packed, const int* __restrict__ noff,
        int nodes, int* __restrict__ csr) {
    __shared__ int cur[NPB];
    const int tid = threadIdx.x;
    const int ubase = blockIdx.x << NPB_LOG2;
    const int nin = min(NPB, nodes - ubase);
    if (tid < nin) cur[tid] = noff[ubase + tid];
    __syncthreads();
    const int jbeg = noff[ubase];
    const int jend = noff[ubase + nin];
    for (int j = jbeg + tid; j < jend; j += 256) {
        uint32_t p = packed[j];
        int local = (int)(p >> 16) - ubase;
        int slot = atomicAdd(&cur[local], 1);
        csr[slot] = (int)(p & 0xffffu);
    }
}

__global__ __launch_bounds__(256) void gather_kernel(const float* __restrict__ x_src,
                                                     const int* __restrict__ nbr,
                                                     const int* __restrict__ off,
                                                     const float* __restrict__ isd_dst,
                                                     const float* __restrict__ isd_src,
                                                     float* __restrict__ out, int n_rows) {
    const int lane = threadIdx.x & 63;
    const int row  = blockIdx.x * 4 + (threadIdx.x >> 6);
    if (row >= n_rows) return;
    const int jbeg = off[row];
    const int jend = off[row + 1];
    const float wd = isd_dst[row];
    float ax = 0.f, ay = 0.f;
    if (jbeg < jend) {
        int sidx = nbr[jbeg];
        for (int j = jbeg; j < jend; ++j) {
            int snext = (j + 1 < jend) ? nbr[j + 1] : 0;
            float w = wd * isd_src[sidx];
            const float2 v = *reinterpret_cast<const float2*>(x_src + (size_t)sidx * 128 + lane * 2);
            ax = fmaf(v.x, w, ax);
            ay = fmaf(v.y, w, ay);
            sidx = snext;
        }
    }
    float2 r; r.x = ax; r.y = ay;
    *reinterpret_cast<float2*>(out + (size_t)row * 128 + lane * 2) = r;
}

__global__ __launch_bounds__(256) void scatter_kernel(const float* __restrict__ spot_x,
                                                      const float* __restrict__ user_x,
                                                      const int* __restrict__ u,
                                                      const int* __restrict__ s, int E,
                                                      const float* __restrict__ isd_u,
                                                      const float* __restrict__ isd_s,
                                                      float* __restrict__ spot_out,
                                                      float* __restrict__ user_out) {
    const int lane = threadIdx.x & 63;
    const int e = blockIdx.x * 4 + (threadIdx.x >> 6);
    if (e >= E) return;
    const int uu = u[e], ss = s[e];
    const float w = isd_u[uu] * isd_s[ss];
    const float2 sv = *reinterpret_cast<const float2*>(spot_x + (size_t)ss * 128 + lane * 2);
    const float2 uv = *reinterpret_cast<const float2*>(user_x + (size_t)uu * 128 + lane * 2);
    atomicAdd(&user_out[(size_t)uu * 128 + lane * 2 + 0], sv.x * w);
    atomicAdd(&user_out[(size_t)uu * 128 + lane * 2 + 1], sv.y * w);
    atomicAdd(&spot_out[(size_t)ss * 128 + lane * 2 + 0], uv.x * w);
    atomicAdd(&spot_out[(size_t)ss * 128 + lane * 2 + 1], uv.y * w);
}

static inline char* align256(char* p) {
    return (char*)(((uintptr_t)p + 255u) & ~(uintptr_t)255u);
}

extern "C" void kernel_launch(void* const* d_in, const int* in_sizes, int n_in,
                              void* d_out, int out_size, void* d_ws, size_t ws_size,
                              hipStream_t stream) {
    const float* spot_x = (const float*)d_in[0];
    const float* user_x = (const float*)d_in[1];
    const int*   edges  = (const int*)d_in[2];
    const int M = in_sizes[0] / 128;   // spots
    const int N = in_sizes[1] / 128;   // users
    const int E = in_sizes[2] / 2;
    const int* u = edges;        // user_spot[0]
    const int* s = edges + E;    // user_spot[1]
    float* spot_out = (float*)d_out;
    float* user_out = (float*)d_out + (size_t)M * 128;

    const int nbu = (N + NPB - 1) / NPB;
    const int nbs = (M + NPB - 1) / NPB;
    const int nm = (N > M) ? N : M;
    const int gpart = (E + PART_CHUNK - 1) / PART_CHUNK;
    const int gscan = ((E + CSCAN_CH - 1) / CSCAN_CH + 3) / 4;

    // ---------------- fast-path layout (deg-free, 2 edge buffers) ----------
    {
        char* ws = (char*)d_ws;
        float*    isd_u = (float*)ws; ws = align256(ws + sizeof(float) * (size_t)N);
        float*    isd_s = (float*)ws; ws = align256(ws + sizeof(float) * (size_t)M);
        int*      bd    = (int*)ws;   ws = align256(ws + sizeof(int) * (size_t)(nbu + nbs));
        int*      buoff = (int*)ws;   ws = align256(ws + sizeof(int) * (size_t)(nbu + 1));
        int*      bsoff = (int*)ws;   ws = align256(ws + sizeof(int) * (size_t)(nbs + 1));
        int*      gcu   = (int*)ws;   ws = align256(ws + sizeof(int) * (size_t)nbu);
        int*      gcs   = (int*)ws;   ws = align256(ws + sizeof(int) * (size_t)nbs);
        uint32_t* bufU  = (uint32_t*)ws; ws = align256(ws + sizeof(uint32_t) * (size_t)E);
        uint32_t* bufS  = (uint32_t*)ws; ws = align256(ws + sizeof(uint32_t) * (size_t)E);
        ushort*   xb    = (ushort*)ws;   // union: spot table, then user table
        size_t fast_needed = (size_t)(ws - (char*)d_ws) + sizeof(ushort) * ((size_t)nm * 128);

        if (fast_needed <= ws_size && nbu <= MAXB && nbs <= MAXB) {
            hipMemsetAsync(bd, 0, sizeof(int) * (size_t)(nbu + nbs), stream);
            hipMemsetAsync(d_out, 0, sizeof(float) * (size_t)out_size, stream);
            bhist_kernel<<<(E + BH_CHUNK - 1) / BH_CHUNK, 256, 0, stream>>>(
                u, s, E, nbu, nbs, bd);
            scan2_kernel<<<2, 1024, 0, stream>>>(bd, nbu, nbs, buoff, bsoff, gcu, gcs);
            part_kernel<<<gpart, 256, 0, stream>>>(u, s, E, nbu, gcu, bufU);
            part_kernel<<<gpart, 256, 0, stream>>>(s, u, E, nbs, gcs, bufS);
            bsort3_kernel<<<nbu, 256, 0, stream>>>(bufU, buoff, isd_u, N);
            bsort3_kernel<<<nbs, 256, 0, stream>>>(bufS, bsoff, isd_s, M);
            // user direction: spot table scaled by isd_s, flush by isd_u
            convert_kernel<<<((M << 6) + 255) / 256, 256, 0, stream>>>(spot_x, isd_s, xb, M);
            cscan_kernel<<<gscan, 256, 0, stream>>>(xb, bufU, E, isd_u, user_out);
            // spot direction: user table (same union slot) scaled by isd_u
            convert_kernel<<<((N << 6) + 255) / 256, 256, 0, stream>>>(user_x, isd_u, xb, N);
            cscan_kernel<<<gscan, 256, 0, stream>>>(xb, bufS, E, isd_s, spot_out);
            return;
        }
    }

    // ---------------- fallback layouts (round-4 proven) --------------------
    char* ws = (char*)d_ws;
    int*      udeg  = (int*)ws;  ws = align256(ws + sizeof(int) * (size_t)(N + M));
    int*      sdeg  = udeg + N;
    float*    isd_u = (float*)ws; ws = align256(ws + sizeof(float) * (size_t)N);
    float*    isd_s = (float*)ws; ws = align256(ws + sizeof(float) * (size_t)M);
    size_t fallback_needed = (size_t)(ws - (char*)d_ws);
    int*      uoff  = (int*)ws;  ws = align256(ws + sizeof(int) * (size_t)(N + 1));
    int*      soff  = (int*)ws;  ws = align256(ws + sizeof(int) * (size_t)(M + 1));
    int*      bdu   = (int*)ws;  ws = align256(ws + sizeof(int) * (size_t)nbu);
    int*      bds   = (int*)ws;  ws = align256(ws + sizeof(int) * (size_t)nbs);
    int*      buoff = (int*)ws;  ws = align256(ws + sizeof(int) * (size_t)(nbu + 1));
    int*      bsoff = (int*)ws;  ws = align256(ws + sizeof(int) * (size_t)(nbs + 1));
    int*      gcu   = (int*)ws;  ws = align256(ws + sizeof(int) * (size_t)nbu);
    int*      gcs   = (int*)ws;  ws = align256(ws + sizeof(int) * (size_t)nbs);
    uint32_t* bufA  = (uint32_t*)ws; ws = align256(ws + sizeof(uint32_t) * (size_t)E);
    char* mark = ws;
    ushort*   xbs   = (ushort*)mark;
    ushort*   xbu   = (ushort*)align256(mark + sizeof(ushort) * ((size_t)M * 128));
    size_t new_needed = (size_t)((char*)xbu - (char*)d_ws) + sizeof(ushort) * ((size_t)N * 128);
    int*      bufB  = (int*)mark;
    size_t old_needed = (size_t)(mark - (char*)d_ws) + sizeof(int) * (size_t)E;

    hipMemsetAsync(udeg, 0, sizeof(int) * (size_t)(N + M), stream);
    deg_kernel<<<(E / 4 + 255) / 256, 256, 0, stream>>>(u, s, E, udeg, sdeg);
    init_isd_kernel<<<(nm + 255) / 256, 256, 0, stream>>>(udeg, sdeg, isd_u, isd_s, N, M);

    if (new_needed <= ws_size && nbu <= MAXB && nbs <= MAXB) {
        convert_kernel<<<((M << 6) + 255) / 256, 256, 0, stream>>>(spot_x, isd_s, xbs, M);
        convert_kernel<<<((N << 6) + 255) / 256, 256, 0, stream>>>(user_x, isd_u, xbu, N);
        breduce_kernel<<<((nbu + nbs) * 64 + 255) / 256, 256, 0, stream>>>(
            udeg, sdeg, N, M, nbu, nbs, bdu, bds);
        scan_kernel<<<1, 1024, 0, stream>>>(bdu, buoff, nbu);
        scan_kernel<<<1, 1024, 0, stream>>>(bds, bsoff, nbs);
        gcur3_init_kernel<<<(nbs + nbu + 255) / 256, 256, 0, stream>>>(
            buoff, bsoff, gcu, gcs, nbu, nbs);
        hipMemsetAsync(d_out, 0, sizeof(float) * (size_t)out_size, stream);
        part_kernel<<<gpart, 256, 0, stream>>>(u, s, E, nbu, gcu, bufA);
        bsort3_kernel<<<nbu, 256, 0, stream>>>(bufA, buoff, isd_u, N);
        cscan_kernel<<<gscan, 256, 0, stream>>>(xbs, bufA, E, isd_u, user_out);
        part_kernel<<<gpart, 256, 0, stream>>>(s, u, E, nbs, gcs, bufA);
        bsort3_kernel<<<nbs, 256, 0, stream>>>(bufA, bsoff, isd_s, M);
        cscan_kernel<<<gscan, 256, 0, stream>>>(xbu, bufA, E, isd_s, spot_out);
    } else if (old_needed <= ws_size && nbu <= MAXB && nbs <= MAXB) {
        scan_kernel<<<1, 1024, 0, stream>>>(udeg, uoff, N);
        scan_kernel<<<1, 1024, 0, stream>>>(sdeg, soff, M);
        gcur_init_kernel<<<(nbs + nbu + 255) / 256, 256, 0, stream>>>(uoff, soff, gcu, gcs, nbu, nbs);
        part_kernel<<<gpart, 256, 0, stream>>>(u, s, E, nbu, gcu, bufA);
        bsort_kernel<<<nbu, 256, 0, stream>>>(bufA, uoff, N, bufB);
        gather_kernel<<<(N + 3) / 4, 256, 0, stream>>>(spot_x, bufB, uoff,
                                                       isd_u, isd_s, user_out, N);
        part_kernel<<<gpart, 256, 0, stream>>>(s, u, E, nbs, gcs, bufA);
        bsort_kernel<<<nbs, 256, 0, stream>>>(bufA, soff, M, bufB);
        gather_kernel<<<(M + 3) / 4, 256, 0, stream>>>(user_x, bufB, soff,
                                                       isd_s, isd_u, spot_out, M);
    } else if (fallback_needed <= ws_size) {
        hipMemsetAsync(d_out, 0, sizeof(float) * (size_t)out_size, stream);
        scatter_kernel<<<((size_t)E + 3) / 4, 256, 0, stream>>>(spot_x, user_x, u, s, E,
                                                                isd_u, isd_s, spot_out, user_out);
    }
}